// Round 19
// baseline (1865.803 us; speedup 1.0000x reference)
//
#include <hip/hip_runtime.h>
#include <math.h>

#define CDIM 768
#define NHEADS 12
#define DHEAD 64
#define SEQ 577
#define NBATCH 32
#define MTOK (NBATCH*SEQ)      // 18464
#define NIMG 576
#define NMERGE 288
#define GB 8                   // batches per qkv group
#define NGROUP (NBATCH/GB)     // 4
#define MGRP (GB*SEQ)          // 4616 rows per group
#define MLPCH 3456             // MLP chunk rows (27x128)
#define NKT 10                 // k-tiles per (b,h) in attention

// ---- workspace layout (float offsets), peak ~161.2 MB ----
#define SZ_BH   ((size_t)4*37*24*4096)           // h images / x1/x2 fp32
#define O_BH    ((size_t)0)
#define O_BA    (SZ_BH)                          // att images / h2 images / xn images
#define SZ_BA   ((size_t)145*24*4096)
#define O_BQ    (O_BA + SZ_BA)                   // Q rows + K/V images / fc1o images / sim half
#define SZ_Q    ((size_t)MGRP*CDIM)
#define SZ_IMG  ((size_t)GB*NHEADS*NKT*4096)
#define O_KIMG  (O_BQ + SZ_Q)
#define O_VIMG  (O_KIMG + SZ_IMG)
#define O_SM    (O_VIMG + SZ_IMG)
#define O_MS    (O_SM)
#define O_MASK  (O_SM + (size_t)NBATCH*NIMG)
#define O_POS   (O_MASK + (size_t)NBATCH*NIMG)
#define O_AVG   (O_POS + (size_t)NBATCH*NIMG)
#define O_END   (O_AVG + (size_t)NBATCH*CDIM)
#define NEED_BYTES (O_END * 4)

// ---- weight-plane scratch inside d_out ----
#define OW_QKV  ((size_t)0)
#define OW_FC1  ((size_t)1769472)
#define OW_FC2  ((size_t)4128768)
#define OW_PROJ ((size_t)6488064)

typedef __attribute__((ext_vector_type(8))) short bf16x8;
typedef __attribute__((ext_vector_type(4))) float f32x4;
typedef __attribute__((address_space(1))) const void GAS_cv;
typedef __attribute__((address_space(3))) void LAS_v;

#define RAW_BAR() do { asm volatile("" ::: "memory"); \
    __builtin_amdgcn_s_barrier(); asm volatile("" ::: "memory"); } while (0)

__device__ __forceinline__ unsigned short f2bf(float f) {
    unsigned int u = __float_as_uint(f);
    u += 0x7fff + ((u >> 16) & 1);           // RNE
    return (unsigned short)(u >> 16);
}
__device__ __forceinline__ float bf2f(unsigned short h) {
    return __uint_as_float(((unsigned int)h) << 16);
}

// ---- bijective XCD chunk remaps (m204) ----
__device__ __forceinline__ void xcd_map(int& bx, int& by, int& bz) {
    int gx = gridDim.x, gy = gridDim.y;
    int nwg = gx * gy * gridDim.z;
    int orig = blockIdx.x + gx * (blockIdx.y + gy * blockIdx.z);
    int q = nwg >> 3, r = nwg & 7;
    int xcd = orig & 7, pos = orig >> 3;
    int wg = (xcd < r ? xcd * (q + 1) : r * (q + 1) + (xcd - r) * q) + pos;
    bx = wg % gx;
    int t2 = wg / gx;
    by = t2 % gy;
    bz = t2 / gy;
}
__device__ __forceinline__ void xcd_map_nf(int& bx, int& by, int& bz) {
    int gx = gridDim.x, gy = gridDim.y;
    int nwg = gx * gy * gridDim.z;
    int orig = blockIdx.x + gx * (blockIdx.y + gy * blockIdx.z);
    int q = nwg >> 3, r = nwg & 7;
    int xcd = orig & 7, pos = orig >> 3;
    int wg = (xcd < r ? xcd * (q + 1) : r * (q + 1) + (xcd - r) * q) + pos;
    by = wg % gy;
    int t2 = wg / gy;
    bx = t2 % gx;
    bz = t2 / gx;
}

// ---------------- block reduce (256 threads) ----------------
__device__ __forceinline__ float blk_sum256(float v, float* red) {
    #pragma unroll
    for (int o = 32; o; o >>= 1) v += __shfl_down(v, o);
    if ((threadIdx.x & 63) == 0) red[threadIdx.x >> 6] = v;
    __syncthreads();
    float tot = red[0] + red[1] + red[2] + red[3];
    __syncthreads();
    return tot;
}

// ---------------- LayerNorm -> bf16 hi/lo plane IMAGES ----------------
__global__ __launch_bounds__(256) void ln_split(const float* __restrict__ x,
        const float* __restrict__ g, const float* __restrict__ b,
        unsigned short* __restrict__ img, int rows_per_grp, int imgrows_per_grp) {
    __shared__ float red[4];
    int row = blockIdx.x;
    const float* xr = x + (size_t)row * CDIM;
    int t = threadIdx.x;
    float v0 = xr[t], v1 = xr[t + 256], v2 = xr[t + 512];
    float mu = blk_sum256(v0 + v1 + v2, red) * (1.f / CDIM);
    float d0 = v0 - mu, d1 = v1 - mu, d2 = v2 - mu;
    float var = blk_sum256(d0 * d0 + d1 * d1 + d2 * d2, red) * (1.f / CDIM);
    float e = var + 1e-5f;
    float rs = rsqrtf(e);
    rs = rs * (1.5f - 0.5f * e * rs * rs);
    float vals[3] = {d0 * rs * g[t] + b[t],
                     d1 * rs * g[t + 256] + b[t + 256],
                     d2 * rs * g[t + 512] + b[t + 512]};
    int grp = row / rows_per_grp;
    int local = row - grp * rows_per_grp;
    int r2 = local & 127;
    size_t ibase = ((size_t)grp * imgrows_per_grp + (local >> 7)) * 24;
    int swz = (r2 & 7) << 4;
    #pragma unroll
    for (int cc = 0; cc < 3; cc++) {
        int col = t + cc * 256;
        int ks = col >> 5, kc = col & 31;
        unsigned char* ip = (unsigned char*)img + ((ibase + ks) << 14) + r2 * 128;
        float v = vals[cc];
        unsigned short hh = f2bf(v);
        unsigned short ll = f2bf(v - bf2f(hh));
        *(unsigned short*)(ip + ((2 * kc) ^ swz)) = hh;
        *(unsigned short*)(ip + ((64 + 2 * kc) ^ swz)) = ll;
    }
}

// ---------------- normalize img tokens -> plane IMAGES (per batch-half) ------
__global__ __launch_bounds__(256) void xn_split(const float* __restrict__ x2,
        unsigned short* __restrict__ img, int b0) {
    __shared__ float red[4];
    int tok = blockIdx.x;
    int bl = tok / NIMG, n = tok % NIMG;
    const float* xr = x2 + ((size_t)(b0 + bl) * SEQ + 1 + n) * CDIM;
    int t = threadIdx.x;
    float v0 = xr[t], v1 = xr[t + 256], v2 = xr[t + 512];
    float ss = blk_sum256(v0 * v0 + v1 * v1 + v2 * v2, red);
    float nrm = fmaxf(sqrtf(ss), 1e-12f);
    float inv = 1.f / nrm;
    float vals[3] = {v0 * inv, v1 * inv, v2 * inv};
    int r2 = n & 127;
    size_t ibase = ((size_t)bl * 5 + (n >> 7)) * 24;
    int swz = (r2 & 7) << 4;
    #pragma unroll
    for (int cc = 0; cc < 3; cc++) {
        int col = t + cc * 256;
        int ks = col >> 5, kc = col & 31;
        unsigned char* ip = (unsigned char*)img + ((ibase + ks) << 14) + r2 * 128;
        float v = vals[cc];
        unsigned short hh = f2bf(v);
        unsigned short ll = f2bf(v - bf2f(hh));
        *(unsigned short*)(ip + ((2 * kc) ^ swz)) = hh;
        *(unsigned short*)(ip + ((64 + 2 * kc) ^ swz)) = ll;
    }
}

// ---------------- weight split: fp32 -> bf16 hi/lo LDS-image planes ----------------
__global__ __launch_bounds__(256) void wsplit_kernel(const float* __restrict__ w,
        unsigned short* __restrict__ wp, int nksteps, int ldw) {
    int bid = blockIdx.x;
    int nt = bid / nksteps, ks = bid % nksteps;
    int t = threadIdx.x;
    int srow = t >> 3, sj = t & 7;
    unsigned short* img = wp + ((size_t)bid << 13);
    #pragma unroll
    for (int i = 0; i < 4; i++) {
        int r = srow + i * 32;
        float4 v = *(const float4*)(w + (size_t)(nt * 128 + r) * ldw + ks * 32 + sj * 4);
        unsigned short h0 = f2bf(v.x), h1 = f2bf(v.y), h2 = f2bf(v.z), h3 = f2bf(v.w);
        ushort4 hv = make_ushort4(h0, h1, h2, h3);
        ushort4 lv = make_ushort4(f2bf(v.x - bf2f(h0)), f2bf(v.y - bf2f(h1)),
                                  f2bf(v.z - bf2f(h2)), f2bf(v.w - bf2f(h3)));
        int swz = (r & 7) << 4;
        int ohi = ((8 * sj) ^ swz) >> 1;
        int olo = ((64 + 8 * sj) ^ swz) >> 1;
        *(ushort4*)&img[r * 64 + ohi] = hv;
        *(ushort4*)&img[r * 64 + olo] = lv;
    }
}

// ---------------- GEMM, BOTH operands plane images, 64x64, 2-DEEP pipeline ------
// 3 LDS buffers; step ks+2 issued each iter; vmcnt(8) leaves 2 steps in flight
// => load latency covered by 2 compute-steps. MFMA order identical -> bit-identical.
// EPI: 1 = +bias+res fp32 (res may alias C), 4 = plain fp32 (batched sim),
//      5 = gelu(+bias) -> plane images, 6 = qkv scatter (Q rows + K/Vt images)
template<int EPI>
__global__ __launch_bounds__(256)
void gemm_ppx(const unsigned short* __restrict__ Ap,
              const unsigned short* __restrict__ Bp,
              void* __restrict__ Cv, int ldc,
              const float* __restrict__ bias,
              const float* __restrict__ res,
              int M, int N, int K,
              long long aBatch, long long cBatch,
              unsigned short* __restrict__ Kimg,
              unsigned short* __restrict__ Vimg) {
    __shared__ unsigned short Asl[3][64 * 64];   // 24 KB
    __shared__ unsigned short Bsl[3][64 * 64];   // 24 KB
    int bx, by, bz;
    xcd_map_nf(bx, by, bz);
    const int t = threadIdx.x;
    const int lane = t & 63, wid = t >> 6;
    const int wr = wid >> 1, wc = wid & 1;
    const unsigned char* ApB = (const unsigned char*)(Ap + ((size_t)bz * aBatch << 13));
    const unsigned char* BpB = (const unsigned char*)(Bp + ((size_t)bz * aBatch << 13));
    float* C = (float*)Cv + (EPI == 4 ? (size_t)bz * cBatch : 0);

    f32x4 acc[2][2];
    #pragma unroll
    for (int i = 0; i < 2; i++)
        #pragma unroll
        for (int j = 0; j < 2; j++) {
            f32x4 z = {0.f, 0.f, 0.f, 0.f};
            acc[i][j] = z;
        }

    const int nsteps = K >> 5;   // >= 24 for all call sites
    const size_t offA = ((size_t)(bx >> 1) * nsteps << 14) + ((size_t)(bx & 1) << 13);
    const size_t offB = ((size_t)(by >> 1) * nsteps << 14) + ((size_t)(by & 1) << 13);
    // prologue: issue steps 0 and 1 into buffers 0 and 1 (8 glds/wave in flight)
    #pragma unroll
    for (int pre = 0; pre < 2; pre++) {
        const unsigned char* imgA = ApB + offA + ((size_t)pre << 14);
        const unsigned char* imgB = BpB + offB + ((size_t)pre << 14);
        #pragma unroll
        for (int i = 0; i < 2; i++) {
            int chunk = (i << 2) | wid;
            __builtin_amdgcn_global_load_lds((GAS_cv*)(imgA + chunk * 1024 + lane * 16),
                (LAS_v*)((unsigned char*)Asl[pre] + chunk * 1024), 16, 0, 0);
            __builtin_amdgcn_global_load_lds((GAS_cv*)(imgB + chunk * 1024 + lane * 16),
                (LAS_v*)((unsigned char*)Bsl[pre] + chunk * 1024), 16, 0, 0);
        }
    }
    for (int ks = 0; ks < nsteps; ks++) {
        const int kn = (ks + 2 < nsteps) ? ks + 2 : nsteps - 1;   // clamp: vmcnt const
        const int bn = (ks + 2) % 3;
        RAW_BAR();   // all waves finished reading buf[bn] (== buf[(ks-1)%3], read iter ks-1)
        {
            const unsigned char* imgA = ApB + offA + ((size_t)kn << 14);
            const unsigned char* imgB = BpB + offB + ((size_t)kn << 14);
            #pragma unroll
            for (int i = 0; i < 2; i++) {
                int chunk = (i << 2) | wid;
                __builtin_amdgcn_global_load_lds((GAS_cv*)(imgA + chunk * 1024 + lane * 16),
                    (LAS_v*)((unsigned char*)Asl[bn] + chunk * 1024), 16, 0, 0);
                __builtin_amdgcn_global_load_lds((GAS_cv*)(imgB + chunk * 1024 + lane * 16),
                    (LAS_v*)((unsigned char*)Bsl[bn] + chunk * 1024), 16, 0, 0);
            }
        }
        asm volatile("s_waitcnt vmcnt(8)" ::: "memory");   // step-ks loads done; 8 newer in flight
        __builtin_amdgcn_sched_barrier(0);
        RAW_BAR();   // all waves' step-ks loads landed
        const int bc = ks % 3;
        const int fr = lane & 15, kg = lane >> 4;
        bf16x8 ah[2], al[2], bh[2], bl[2];
        #pragma unroll
        for (int m = 0; m < 2; m++) {
            int r = wr * 32 + m * 16 + fr;
            int swz = (r & 7) << 4;
            const unsigned char* base = (const unsigned char*)Asl[bc] + r * 128;
            ah[m] = *(const bf16x8*)(base + ((16 * kg) ^ swz));
            al[m] = *(const bf16x8*)(base + ((64 + 16 * kg) ^ swz));
        }
        #pragma unroll
        for (int n = 0; n < 2; n++) {
            int r = wc * 32 + n * 16 + fr;
            int swz = (r & 7) << 4;
            const unsigned char* base = (const unsigned char*)Bsl[bc] + r * 128;
            bh[n] = *(const bf16x8*)(base + ((16 * kg) ^ swz));
            bl[n] = *(const bf16x8*)(base + ((64 + 16 * kg) ^ swz));
        }
        #pragma unroll
        for (int m = 0; m < 2; m++)
            #pragma unroll
            for (int n = 0; n < 2; n++) {
                acc[m][n] = __builtin_amdgcn_mfma_f32_16x16x32_bf16(ah[m], bh[n], acc[m][n], 0, 0, 0);
                acc[m][n] = __builtin_amdgcn_mfma_f32_16x16x32_bf16(ah[m], bl[n], acc[m][n], 0, 0, 0);
                acc[m][n] = __builtin_amdgcn_mfma_f32_16x16x32_bf16(al[m], bh[n], acc[m][n], 0, 0, 0);
            }
    }

    const int fr = lane & 15, fq = lane >> 4;
    const int m0 = bx * 64, n0 = by * 64;
    #pragma unroll
    for (int m = 0; m < 2; m++) {
        #pragma unroll
        for (int rr = 0; rr < 4; rr++) {
            int row = m0 + wr * 32 + m * 16 + fq * 4 + rr;
            if (row >= M) continue;
            #pragma unroll
            for (int n = 0; n < 2; n++) {
                int col = n0 + wc * 32 + n * 16 + fr;
                float v = acc[m][n][rr];
                size_t ci = (size_t)row * ldc + col;
                if (EPI == 1) {
                    C[ci] = v + bias[col] + res[ci];
                } else if (EPI == 4) {
                    C[ci] = v;
                } else if (EPI == 5) {
                    v += bias[col];
                    v = 0.5f * v * (1.0f + erff(v * 0.70710678118654752f));
                    unsigned short hh = f2bf(v);
                    unsigned short ll = f2bf(v - bf2f(hh));
                    unsigned char* img = (unsigned char*)Cv +
                        (((size_t)(row >> 7) * (ldc >> 5) + (col >> 5)) << 14);
                    int r2 = row & 127, swz2 = (r2 & 7) << 4, kc = col & 31;
                    *(unsigned short*)(img + r2 * 128 + ((2 * kc) ^ swz2)) = hh;
                    *(unsigned short*)(img + r2 * 128 + ((64 + 2 * kc) ^ swz2)) = ll;
                } else { // 6: qkv scatter (head = (col>>6)-12 for K, -24 for V)
                    float v2 = v + bias[col];
                    if (col < 768) {
                        ((float*)Cv)[(size_t)row * 768 + col] = v2;
                    } else {
                        int b_local = row / SEQ;
                        int s = row - b_local * SEQ;
                        int dloc = col & 63;
                        int kt = s >> 6, r2 = s & 63;
                        unsigned short hh = f2bf(v2);
                        unsigned short ll = f2bf(v2 - bf2f(hh));
                        if (col < 1536) {
                            int hh_i = (col >> 6) - 12;
                            size_t imgi = (((size_t)b_local * NHEADS + hh_i) * NKT + kt) << 14;
                            unsigned char* img = (unsigned char*)Kimg + imgi;
                            int off = (2 * dloc) ^ ((r2 & 7) << 4);
                            *(unsigned short*)(img + r2 * 256 + off) = hh;
                            *(unsigned short*)(img + r2 * 256 + 128 + off) = ll;
                        } else {
                            int hh_i = (col >> 6) - 24;
                            size_t imgi = (((size_t)b_local * NHEADS + hh_i) * NKT + kt) << 14;
                            unsigned char* img = (unsigned char*)Vimg + imgi;
                            int off = (2 * r2) ^ ((dloc & 7) << 4);
                            *(unsigned short*)(img + dloc * 256 + off) = hh;
                            *(unsigned short*)(img + dloc * 256 + 128 + off) = ll;
                        }
                    }
                }
            }
        }
    }
}

// ---------------- MFMA flash attention: K/Vt images in, O images out ----------------
__global__ __launch_bounds__(256) void attn_glds(const float* __restrict__ Qb,
        const unsigned short* __restrict__ Kimg, const unsigned short* __restrict__ Vimg,
        unsigned short* __restrict__ attimg, int row0) {
    int bx, by, bz;
    xcd_map(bx, by, bz);
    const int b = bz, h = by, q0 = bx * 64;
    const int t = threadIdx.x;
    const int lane = t & 63, wid = t >> 6;
    const int fr = lane & 15, kg = lane >> 4;
    __shared__ unsigned short Khl[64 * 128];
    __shared__ unsigned short Vt[64 * 128];
    __shared__ unsigned char Pbuf[16384];
    unsigned char* KhlB = (unsigned char*)Khl;
    unsigned char* VtB = (unsigned char*)Vt;
    unsigned char* PwB = Pbuf + wid * 4096;
    const unsigned char* KiB = (const unsigned char*)Kimg + (((size_t)b * NHEADS + h) * NKT << 14);
    const unsigned char* ViB = (const unsigned char*)Vimg + (((size_t)b * NHEADS + h) * NKT << 14);

    bf16x8 qh[2], qlo[2];
    {
        int qrow = q0 + wid * 16 + fr; qrow = qrow < SEQ ? qrow : SEQ - 1;
        const float* qbase = Qb + ((size_t)b * SEQ + qrow) * CDIM + h * DHEAD;
        #pragma unroll
        for (int ds = 0; ds < 2; ds++) {
            float tmp[8];
            *(float4*)(tmp)     = *(const float4*)(qbase + ds * 32 + kg * 8);
            *(float4*)(tmp + 4) = *(const float4*)(qbase + ds * 32 + kg * 8 + 4);
            #pragma unroll
            for (int j = 0; j < 8; j++) {
                unsigned short hh = f2bf(tmp[j]);
                qh[ds][j]  = (short)hh;
                qlo[ds][j] = (short)f2bf(tmp[j] - bf2f(hh));
            }
        }
    }

    f32x4 acc_o[4];
    #pragma unroll
    for (int i = 0; i < 4; i++) { f32x4 z = {0.f,0.f,0.f,0.f}; acc_o[i] = z; }
    float m_run[4] = {-1e30f, -1e30f, -1e30f, -1e30f};
    float l_run[4] = {0.f, 0.f, 0.f, 0.f};

    for (int kt = 0; kt < NKT; kt++) {
        const int c0 = kt * 64;
        __syncthreads();
        {
            const unsigned char* ki = KiB + ((size_t)kt << 14);
            const unsigned char* vi = ViB + ((size_t)kt << 14);
            #pragma unroll
            for (int i = 0; i < 4; i++) {
                int chunk = (i << 2) | wid;
                __builtin_amdgcn_global_load_lds((GAS_cv*)(ki + chunk * 1024 + lane * 16),
                    (LAS_v*)(KhlB + chunk * 1024), 16, 0, 0);
                __builtin_amdgcn_global_load_lds((GAS_cv*)(vi + chunk * 1024 + lane * 16),
                    (LAS_v*)(VtB + chunk * 1024), 16, 0, 0);
            }
        }
        __syncthreads();
        f32x4 s[4];
        #pragma unroll
        for (int i = 0; i < 4; i++) { f32x4 z = {0.f,0.f,0.f,0.f}; s[i] = z; }
        #pragma unroll
        for (int ds = 0; ds < 2; ds++) {
            #pragma unroll
            for (int n = 0; n < 4; n++) {
                int r = n * 16 + fr;
                int swz = (r & 7) << 4;
                const unsigned char* rb = KhlB + r * 256;
                bf16x8 kh = *(const bf16x8*)(rb + ((ds * 64 + kg * 16) ^ swz));
                bf16x8 kl = *(const bf16x8*)(rb + 128 + ((ds * 64 + kg * 16) ^ swz));
                s[n] = __builtin_amdgcn_mfma_f32_16x16x32_bf16(qh[ds], kh, s[n], 0, 0, 0);
                s[n] = __builtin_amdgcn_mfma_f32_16x16x32_bf16(qh[ds], kl, s[n], 0, 0, 0);
                s[n] = __builtin_amdgcn_mfma_f32_16x16x32_bf16(qlo[ds], kh, s[n], 0, 0, 0);
            }
        }
        float p[4][4];
        #pragma unroll
        for (int n = 0; n < 4; n++) {
            int kcol = c0 + n * 16 + fr;
            #pragma unroll
            for (int r = 0; r < 4; r++) {
                float sv = s[n][r] * 0.125f;
                if (kcol >= SEQ) sv = -1e30f;
                p[n][r] = sv;
            }
        }
        float corr[4];
        #pragma unroll
        for (int r = 0; r < 4; r++) {
            float mx = fmaxf(fmaxf(p[0][r], p[1][r]), fmaxf(p[2][r], p[3][r]));
            mx = fmaxf(mx, __shfl_xor(mx, 1));
            mx = fmaxf(mx, __shfl_xor(mx, 2));
            mx = fmaxf(mx, __shfl_xor(mx, 4));
            mx = fmaxf(mx, __shfl_xor(mx, 8));
            float mnew = fmaxf(m_run[r], mx);
            corr[r] = __expf(m_run[r] - mnew);
            m_run[r] = mnew;
            float ls = 0.f;
            #pragma unroll
            for (int n = 0; n < 4; n++) {
                p[n][r] = __expf(p[n][r] - mnew);
                ls += p[n][r];
            }
            ls += __shfl_xor(ls, 1);
            ls += __shfl_xor(ls, 2);
            ls += __shfl_xor(ls, 4);
            ls += __shfl_xor(ls, 8);
            l_run[r] = l_run[r] * corr[r] + ls;
        }
        #pragma unroll
        for (int nd = 0; nd < 4; nd++)
            #pragma unroll
            for (int r = 0; r < 4; r++)
                acc_o[nd][r] *= corr[r];
        {
            int qb = (lane >> 4) * 4;
            #pragma unroll
            for (int n = 0; n < 4; n++) {
                int kcol = n * 16 + fr;
                #pragma unroll
                for (int r = 0; r < 4; r++) {
                    int qq = qb + r;
                    unsigned short ph = f2bf(p[n][r]);
                    unsigned short pl = f2bf(p[n][r] - bf2f(ph));
                    int off = (kcol * 2) ^ ((qq & 7) << 4);
                    *(unsigned short*)(PwB + qq * 256 + off) = ph;
                    *(unsigned short*)(PwB + qq * 256 + 128 + off) = pl;
                }
            }
        }
        #pragma unroll
        for (int ks = 0; ks < 2; ks++) {
            int swzp = (fr & 7) << 4;
            bf16x8 pah = *(const bf16x8*)(PwB + fr * 256 + ((ks * 64 + kg * 16) ^ swzp));
            bf16x8 pal = *(const bf16x8*)(PwB + fr * 256 + 128 + ((ks * 64 + kg * 16) ^ swzp));
            #pragma unroll
            for (int nd = 0; nd < 4; nd++) {
                int rv = nd * 16 + fr;
                int swzv = (rv & 7) << 4;
                const unsigned char* rb = VtB + rv * 256;
                bf16x8 vh = *(const bf16x8*)(rb + ((ks * 64 + kg * 16) ^ swzv));
                bf16x8 vl = *(const bf16x8*)(rb + 128 + ((ks * 64 + kg * 16) ^ swzv));
                acc_o[nd] = __builtin_amdgcn_mfma_f32_16x16x32_bf16(pah, vh, acc_o[nd], 0, 0, 0);
                acc_o[nd] = __builtin_amdgcn_mfma_f32_16x16x32_bf16(pah, vl, acc_o[nd], 0, 0, 0);
                acc_o[nd] = __builtin_amdgcn_mfma_f32_16x16x32_bf16(pal, vh, acc_o[nd], 0, 0, 0);
            }
        }
    }
    // epilogue: O -> plane images (global row index)
    #pragma unroll
    for (int r = 0; r < 4; r++) {
        int q = q0 + wid * 16 + (lane >> 4) * 4 + r;
        if (q >= SEQ) continue;
        float inv = 1.f / l_run[r];
        int grow = row0 + b * SEQ + q;
        int r2 = grow & 127;
        size_t ibase = (size_t)(grow >> 7) * 24;
        int swz = (r2 & 7) << 4;
        #pragma unroll
        for (int nd = 0; nd < 4; nd++) {
            int col = h * DHEAD + nd * 16 + fr;
            float v = acc_o[nd][r] * inv;
            unsigned short hh = f2bf(v);
            unsigned short ll = f2bf(v - bf2f(hh));
            unsigned char* ip = (unsigned char*)attimg + ((ibase + (col >> 5)) << 14) + r2 * 128;
            int kc = col & 31;
            *(unsigned short*)(ip + ((2 * kc) ^ swz)) = hh;
            *(unsigned short*)(ip + ((64 + 2 * kc) ^ swz)) = ll;
        }
    }
}

// ---------------- row max of symmetrized sim (excluding diagonal) ----------------
__global__ __launch_bounds__(64) void rowmax_kernel(const float* __restrict__ sim,
                                                    float* __restrict__ ms) {
    int row = blockIdx.x;
    int b = row / NIMG, n = row % NIMG;
    const float* sb = sim + (size_t)b * NIMG * NIMG;
    int lane = threadIdx.x;
    float mx = -1e30f;
    #pragma unroll
    for (int i = 0; i < NIMG / 64; i++) {
        int m = lane + i * 64;
        if (m != n) {
            float v = 0.5f * (sb[(size_t)n * NIMG + m] + sb[(size_t)m * NIMG + n]);
            mx = fmaxf(mx, v);
        }
    }
    #pragma unroll
    for (int o = 32; o; o >>= 1) mx = fmaxf(mx, __shfl_down(mx, o));
    if (lane == 0) ms[row] = mx;
}

// ---------------- exact top-k selection with lax.top_k tie semantics ----------------
__global__ __launch_bounds__(576) void select_kernel(const float* __restrict__ ms,
        int* __restrict__ mergemask, int* __restrict__ keeppos) {
    __shared__ float v[NIMG];
    __shared__ int keepf[NIMG];
    int b = blockIdx.x;
    int n = threadIdx.x;
    v[n] = ms[b * NIMG + n];
    __syncthreads();
    float vn = v[n];
    int rank_desc = 0, rank_asc = 0;
    for (int m = 0; m < NIMG; m++) {
        float vm = v[m];
        int tie_lo = (vm == vn && m < n);
        rank_desc += (vm > vn) || tie_lo;
        rank_asc  += (vm < vn) || tie_lo;
    }
    int merge = rank_desc < NMERGE;
    int keep  = rank_asc  < NMERGE;
    mergemask[b * NIMG + n] = merge;
    keepf[n] = keep;
    __syncthreads();
    if (keep) {
        int pos = 0;
        for (int m = 0; m < n; m++) pos += keepf[m];
        keeppos[b * NIMG + n] = pos;
    } else {
        keeppos[b * NIMG + n] = -1;
    }
}

// ---------------- average of merged tokens (parallelized) ----------------
__global__ __launch_bounds__(256) void avg_kernel(const float* __restrict__ x2,
        const int* __restrict__ mask, float* __restrict__ avg) {
    __shared__ float4 red[8][33];
    int b = blockIdx.x, cc = blockIdx.y;
    int t = threadIdx.x;
    int rr = t >> 5, c4 = t & 31;
    int c = cc * 128 + c4 * 4;
    const int* mb = mask + b * NIMG;
    float4 s = make_float4(0.f, 0.f, 0.f, 0.f);
    for (int n = rr; n < NIMG; n += 8) {
        if (mb[n]) {
            float4 v = *(const float4*)(x2 + ((size_t)b * SEQ + 1 + n) * CDIM + c);
            s.x += v.x; s.y += v.y; s.z += v.z; s.w += v.w;
        }
    }
    red[rr][c4] = s;
    __syncthreads();
    if (rr == 0) {
        float4 tot = red[0][c4];
        #pragma unroll
        for (int i = 1; i < 8; i++) {
            float4 v = red[i][c4];
            tot.x += v.x; tot.y += v.y; tot.z += v.z; tot.w += v.w;
        }
        float sc1 = 1.f / (float)NMERGE, sc2 = 1.f / (float)(NIMG - NMERGE);
        tot.x = (tot.x * sc1) * sc2; tot.y = (tot.y * sc1) * sc2;
        tot.z = (tot.z * sc1) * sc2; tot.w = (tot.w * sc1) * sc2;
        *(float4*)(avg + (size_t)b * CDIM + c) = tot;
    }
}

// ---------------- assemble output ----------------
__global__ __launch_bounds__(192) void assemble_kernel(const float* __restrict__ x2,
        const int* __restrict__ keeppos, const float* __restrict__ avg,
        float* __restrict__ out) {
    int g = blockIdx.x;
    int b = g / SEQ, s_ = g % SEQ;
    int t = threadIdx.x;
    const float4* src = (const float4*)(x2 + (size_t)g * CDIM);
    if (s_ == 0) {
        float4* dst = (float4*)(out + (size_t)b * 289 * CDIM);
        dst[t] = src[t];
    } else {
        int n = s_ - 1;
        int pos = keeppos[b * NIMG + n];
        if (pos < 0) return;
        const float4* av = (const float4*)(avg + (size_t)b * CDIM);
        float4 v = src[t], a = av[t];
        v.x += a.x; v.y += a.y; v.z += a.z; v.w += a.w;
        float4* dst = (float4*)(out + ((size_t)b * 289 + 1 + pos) * CDIM);
        dst[t] = v;
    }
}

extern "C" void kernel_launch(void* const* d_in, const int* in_sizes, int n_in,
                              void* d_out, int out_size, void* d_ws, size_t ws_size,
                              hipStream_t stream) {
    const float* x      = (const float*)d_in[0];
    const float* qkv_w  = (const float*)d_in[1];
    const float* qkv_b  = (const float*)d_in[2];
    const float* proj_w = (const float*)d_in[3];
    const float* proj_b = (const float*)d_in[4];
    const float* ln1_g  = (const float*)d_in[5];
    const float* ln1_b  = (const float*)d_in[6];
    const float* ln2_g  = (const float*)d_in[7];
    const float* ln2_b  = (const float*)d_in[8];
    const float* fc1_w  = (const float*)d_in[9];
    const float* fc1_b  = (const float*)d_in[10];
    const float* fc2_w  = (const float*)d_in[11];
    const float* fc2_b  = (const float*)d_in[12];

    if (ws_size < NEED_BYTES) return;

    float* ws   = (float*)d_ws;
    float* bh   = ws + O_BH;
    float* ba   = ws + O_BA;
    float* bq   = ws + O_BQ;
    float* qbuf = ws + O_BQ;
    unsigned short* kimg = (unsigned short*)(ws + O_KIMG);
    unsigned short* vimg = (unsigned short*)(ws + O_VIMG);
    float* ms   = ws + O_MS;
    int*   mask = (int*)(ws + O_MASK);
    int*   pos  = (int*)(ws + O_POS);
    float* avg  = ws + O_AVG;
    float* outp = (float*)d_out;

    unsigned short* himg   = (unsigned short*)bh;
    unsigned short* attimg = (unsigned short*)ba;
    unsigned short* h2img  = (unsigned short*)ba;
    unsigned short* xnimg  = (unsigned short*)ba;
    unsigned short* fopl   = (unsigned short*)bq;

    unsigned short* qkvp  = (unsigned short*)(outp + OW_QKV);
    unsigned short* fc1p  = (unsigned short*)(outp + OW_FC1);
    unsigned short* fc2p  = (unsigned short*)(outp + OW_FC2);
    unsigned short* projp = (unsigned short*)(outp + OW_PROJ);

    // 0. split weights; zero V-image scratch
    wsplit_kernel<<<18 * 24, 256, 0, stream>>>(qkv_w, qkvp, 24, CDIM);
    wsplit_kernel<<<24 * 24, 256, 0, stream>>>(fc1_w, fc1p, 24, CDIM);
    wsplit_kernel<<<6 * 96, 256, 0, stream>>>(fc2_w, fc2p, 96, 3072);
    wsplit_kernel<<<6 * 24, 256, 0, stream>>>(proj_w, projp, 24, CDIM);
    hipMemsetAsync(vimg, 0, SZ_IMG * 4, stream);

    // 1. h = LN1(x) -> group-padded plane images in BH
    ln_split<<<MTOK, 256, 0, stream>>>(x, ln1_g, ln1_b, himg, MGRP, 37);

    // 2. per-group qkv (dual-glds 2-deep) + attention -> att images in BA
    for (int g = 0; g < NGROUP; g++) {
        gemm_ppx<6><<<dim3(73, 36), 256, 0, stream>>>(
            himg + (size_t)g * 37 * 24 * 8192, qkvp, (void*)qbuf, 3 * CDIM,
            qkv_b, nullptr, MGRP, 3 * CDIM, CDIM, 0, 0, kimg, vimg);
        attn_glds<<<dim3(NKT, NHEADS, GB), 256, 0, stream>>>(
            qbuf, kimg, vimg, attimg, g * MGRP);
    }

    // 3. x1 = x + att @ proj_w^T + proj_b (dual-glds 2-deep) -> BH fp32
    gemm_ppx<1><<<dim3((MTOK + 63) / 64, 12), 256, 0, stream>>>(
        attimg, projp, (void*)bh, CDIM, proj_b, x, MTOK, CDIM, CDIM,
        0, 0, nullptr, nullptr);

    // 4. h2 = LN2(x1) -> global plane images in BA
    ln_split<<<MTOK, 256, 0, stream>>>(bh, ln2_g, ln2_b, h2img, MTOK, 145);

    // 5. MLP chunks: fc1 (gelu -> fc1o images), fc2 (+res in-place BH)
    for (int c0 = 0; c0 < MTOK; c0 += MLPCH) {
        int mc = (MTOK - c0 < MLPCH) ? (MTOK - c0) : MLPCH;
        float* x1c = bh + (size_t)c0 * CDIM;
        gemm_ppx<5><<<dim3((mc + 63) / 64, 48), 256, 0, stream>>>(
            h2img + (size_t)(c0 >> 7) * 24 * 8192, fc1p, (void*)fopl, 3072,
            fc1_b, nullptr, mc, 3072, CDIM, 0, 0, nullptr, nullptr);
        gemm_ppx<1><<<dim3((mc + 63) / 64, 12), 256, 0, stream>>>(
            fopl, fc2p, (void*)x1c, CDIM, fc2_b, x1c,
            mc, CDIM, 3072, 0, 0, nullptr, nullptr);
    }

    // 6-8. two batch-halves: xn images -> batched sim -> rowmax
    for (int hf = 0; hf < 2; hf++) {
        xn_split<<<16 * NIMG, 256, 0, stream>>>(bh, xnimg, hf * 16);
        gemm_ppx<4><<<dim3(9, 9, 16), 256, 0, stream>>>(
            xnimg, xnimg, (void*)bq, NIMG, nullptr, nullptr,
            NIMG, NIMG, CDIM, 5 * 24, (long long)NIMG * NIMG, nullptr, nullptr);
        rowmax_kernel<<<16 * NIMG, 64, 0, stream>>>(bq, ms + (size_t)hf * 16 * NIMG);
    }

    // 9-11. selection, merged average, assemble
    select_kernel<<<NBATCH, NIMG, 0, stream>>>(ms, mask, pos);
    avg_kernel<<<dim3(NBATCH, 6), 256, 0, stream>>>(bh, mask, avg);
    assemble_kernel<<<MTOK, 192, 0, stream>>>(bh, pos, avg, outp);
}

// Round 20
// 1721.325 us; speedup vs baseline: 1.0839x; 1.0839x over previous
//
#include <hip/hip_runtime.h>
#include <math.h>

#define CDIM 768
#define NHEADS 12
#define DHEAD 64
#define SEQ 577
#define NBATCH 32
#define MTOK (NBATCH*SEQ)      // 18464
#define NIMG 576
#define NMERGE 288
#define GB 8                   // batches per qkv group
#define NGROUP (NBATCH/GB)     // 4
#define MGRP (GB*SEQ)          // 4616 rows per group
#define MLPCH 3456             // MLP chunk rows (27x128)
#define NKT 10                 // k-tiles per (b,h) in attention

// ---- workspace layout (float offsets), peak ~161.2 MB ----
#define SZ_BH   ((size_t)4*37*24*4096)           // h images / x1/x2 fp32
#define O_BH    ((size_t)0)
#define O_BA    (SZ_BH)                          // att images / h2 images / xn images
#define SZ_BA   ((size_t)145*24*4096)
#define O_BQ    (O_BA + SZ_BA)                   // Q rows + K/V images / fc1o images / sim half
#define SZ_Q    ((size_t)MGRP*CDIM)
#define SZ_IMG  ((size_t)GB*NHEADS*NKT*4096)
#define O_KIMG  (O_BQ + SZ_Q)
#define O_VIMG  (O_KIMG + SZ_IMG)
#define O_SM    (O_VIMG + SZ_IMG)
#define O_MS    (O_SM)
#define O_MASK  (O_SM + (size_t)NBATCH*NIMG)
#define O_POS   (O_MASK + (size_t)NBATCH*NIMG)
#define O_AVG   (O_POS + (size_t)NBATCH*NIMG)
#define O_END   (O_AVG + (size_t)NBATCH*CDIM)
#define NEED_BYTES (O_END * 4)

// ---- weight-plane scratch inside d_out ----
#define OW_QKV  ((size_t)0)
#define OW_FC1  ((size_t)1769472)
#define OW_FC2  ((size_t)4128768)
#define OW_PROJ ((size_t)6488064)

typedef __attribute__((ext_vector_type(8))) short bf16x8;
typedef __attribute__((ext_vector_type(4))) float f32x4;
typedef __attribute__((address_space(1))) const void GAS_cv;
typedef __attribute__((address_space(3))) void LAS_v;

#define RAW_BAR() do { asm volatile("" ::: "memory"); \
    __builtin_amdgcn_s_barrier(); asm volatile("" ::: "memory"); } while (0)

__device__ __forceinline__ unsigned short f2bf(float f) {
    unsigned int u = __float_as_uint(f);
    u += 0x7fff + ((u >> 16) & 1);           // RNE
    return (unsigned short)(u >> 16);
}
__device__ __forceinline__ float bf2f(unsigned short h) {
    return __uint_as_float(((unsigned int)h) << 16);
}

// ---- bijective XCD chunk remaps (m204) ----
__device__ __forceinline__ void xcd_map(int& bx, int& by, int& bz) {
    int gx = gridDim.x, gy = gridDim.y;
    int nwg = gx * gy * gridDim.z;
    int orig = blockIdx.x + gx * (blockIdx.y + gy * blockIdx.z);
    int q = nwg >> 3, r = nwg & 7;
    int xcd = orig & 7, pos = orig >> 3;
    int wg = (xcd < r ? xcd * (q + 1) : r * (q + 1) + (xcd - r) * q) + pos;
    bx = wg % gx;
    int t2 = wg / gx;
    by = t2 % gy;
    bz = t2 / gy;
}
// N-fastest with 12-wide by-grouping (when gy%12==0): each XCD's contiguous
// range covers ~(span_bx x 12) tiles -> B panels fetched into ~3 L2s not 8.
// Composition of two bijections (m204 remap + mixed-radix reorder) -> bijective.
__device__ __forceinline__ void xcd_map_nf(int& bx, int& by, int& bz) {
    int gx = gridDim.x, gy = gridDim.y;
    int nwg = gx * gy * gridDim.z;
    int orig = blockIdx.x + gx * (blockIdx.y + gy * blockIdx.z);
    int q = nwg >> 3, r = nwg & 7;
    int xcd = orig & 7, pos = orig >> 3;
    int wg = (xcd < r ? xcd * (q + 1) : r * (q + 1) + (xcd - r) * q) + pos;
    int gxy = gx * gy;
    bz = wg / gxy;
    int rem = wg - bz * gxy;
    if ((gy % 12) == 0) {
        int seg = gx * 12;
        int grp = rem / seg;
        int r2 = rem - grp * seg;
        bx = r2 / 12;
        by = grp * 12 + (r2 - (r2 / 12) * 12);
    } else {
        by = rem % gy;
        bx = rem / gy;
    }
}

// ---------------- block reduce (256 threads) ----------------
__device__ __forceinline__ float blk_sum256(float v, float* red) {
    #pragma unroll
    for (int o = 32; o; o >>= 1) v += __shfl_down(v, o);
    if ((threadIdx.x & 63) == 0) red[threadIdx.x >> 6] = v;
    __syncthreads();
    float tot = red[0] + red[1] + red[2] + red[3];
    __syncthreads();
    return tot;
}

// ---------------- LayerNorm -> bf16 hi/lo plane IMAGES ----------------
__global__ __launch_bounds__(256) void ln_split(const float* __restrict__ x,
        const float* __restrict__ g, const float* __restrict__ b,
        unsigned short* __restrict__ img, int rows_per_grp, int imgrows_per_grp) {
    __shared__ float red[4];
    int row = blockIdx.x;
    const float* xr = x + (size_t)row * CDIM;
    int t = threadIdx.x;
    float v0 = xr[t], v1 = xr[t + 256], v2 = xr[t + 512];
    float mu = blk_sum256(v0 + v1 + v2, red) * (1.f / CDIM);
    float d0 = v0 - mu, d1 = v1 - mu, d2 = v2 - mu;
    float var = blk_sum256(d0 * d0 + d1 * d1 + d2 * d2, red) * (1.f / CDIM);
    float e = var + 1e-5f;
    float rs = rsqrtf(e);
    rs = rs * (1.5f - 0.5f * e * rs * rs);
    float vals[3] = {d0 * rs * g[t] + b[t],
                     d1 * rs * g[t + 256] + b[t + 256],
                     d2 * rs * g[t + 512] + b[t + 512]};
    int grp = row / rows_per_grp;
    int local = row - grp * rows_per_grp;
    int r2 = local & 127;
    size_t ibase = ((size_t)grp * imgrows_per_grp + (local >> 7)) * 24;
    int swz = (r2 & 7) << 4;
    #pragma unroll
    for (int cc = 0; cc < 3; cc++) {
        int col = t + cc * 256;
        int ks = col >> 5, kc = col & 31;
        unsigned char* ip = (unsigned char*)img + ((ibase + ks) << 14) + r2 * 128;
        float v = vals[cc];
        unsigned short hh = f2bf(v);
        unsigned short ll = f2bf(v - bf2f(hh));
        *(unsigned short*)(ip + ((2 * kc) ^ swz)) = hh;
        *(unsigned short*)(ip + ((64 + 2 * kc) ^ swz)) = ll;
    }
}

// ---------------- normalize img tokens -> plane IMAGES (per batch-half) ------
__global__ __launch_bounds__(256) void xn_split(const float* __restrict__ x2,
        unsigned short* __restrict__ img, int b0) {
    __shared__ float red[4];
    int tok = blockIdx.x;
    int bl = tok / NIMG, n = tok % NIMG;
    const float* xr = x2 + ((size_t)(b0 + bl) * SEQ + 1 + n) * CDIM;
    int t = threadIdx.x;
    float v0 = xr[t], v1 = xr[t + 256], v2 = xr[t + 512];
    float ss = blk_sum256(v0 * v0 + v1 * v1 + v2 * v2, red);
    float nrm = fmaxf(sqrtf(ss), 1e-12f);
    float inv = 1.f / nrm;
    float vals[3] = {v0 * inv, v1 * inv, v2 * inv};
    int r2 = n & 127;
    size_t ibase = ((size_t)bl * 5 + (n >> 7)) * 24;
    int swz = (r2 & 7) << 4;
    #pragma unroll
    for (int cc = 0; cc < 3; cc++) {
        int col = t + cc * 256;
        int ks = col >> 5, kc = col & 31;
        unsigned char* ip = (unsigned char*)img + ((ibase + ks) << 14) + r2 * 128;
        float v = vals[cc];
        unsigned short hh = f2bf(v);
        unsigned short ll = f2bf(v - bf2f(hh));
        *(unsigned short*)(ip + ((2 * kc) ^ swz)) = hh;
        *(unsigned short*)(ip + ((64 + 2 * kc) ^ swz)) = ll;
    }
}

// ---------------- weight split: fp32 -> bf16 hi/lo LDS-image planes ----------------
__global__ __launch_bounds__(256) void wsplit_kernel(const float* __restrict__ w,
        unsigned short* __restrict__ wp, int nksteps, int ldw) {
    int bid = blockIdx.x;
    int nt = bid / nksteps, ks = bid % nksteps;
    int t = threadIdx.x;
    int srow = t >> 3, sj = t & 7;
    unsigned short* img = wp + ((size_t)bid << 13);
    #pragma unroll
    for (int i = 0; i < 4; i++) {
        int r = srow + i * 32;
        float4 v = *(const float4*)(w + (size_t)(nt * 128 + r) * ldw + ks * 32 + sj * 4);
        unsigned short h0 = f2bf(v.x), h1 = f2bf(v.y), h2 = f2bf(v.z), h3 = f2bf(v.w);
        ushort4 hv = make_ushort4(h0, h1, h2, h3);
        ushort4 lv = make_ushort4(f2bf(v.x - bf2f(h0)), f2bf(v.y - bf2f(h1)),
                                  f2bf(v.z - bf2f(h2)), f2bf(v.w - bf2f(h3)));
        int swz = (r & 7) << 4;
        int ohi = ((8 * sj) ^ swz) >> 1;
        int olo = ((64 + 8 * sj) ^ swz) >> 1;
        *(ushort4*)&img[r * 64 + ohi] = hv;
        *(ushort4*)&img[r * 64 + olo] = lv;
    }
}

// ---------------- GEMM, BOTH operands plane images, 64x64, counted-vmcnt ------
// (round-18 proven 1-deep / 2-buffer pipeline)
// EPI: 1 = +bias+res fp32 (res may alias C), 4 = plain fp32 (batched sim),
//      5 = gelu(+bias) -> plane images, 6 = qkv scatter (Q rows + K/Vt images)
template<int EPI>
__global__ __launch_bounds__(256)
void gemm_ppx(const unsigned short* __restrict__ Ap,
              const unsigned short* __restrict__ Bp,
              void* __restrict__ Cv, int ldc,
              const float* __restrict__ bias,
              const float* __restrict__ res,
              int M, int N, int K,
              long long aBatch, long long cBatch,
              unsigned short* __restrict__ Kimg,
              unsigned short* __restrict__ Vimg) {
    __shared__ unsigned short Asl[2][64 * 64];
    __shared__ unsigned short Bsl[2][64 * 64];
    int bx, by, bz;
    xcd_map_nf(bx, by, bz);
    const int t = threadIdx.x;
    const int lane = t & 63, wid = t >> 6;
    const int wr = wid >> 1, wc = wid & 1;
    const unsigned char* ApB = (const unsigned char*)(Ap + ((size_t)bz * aBatch << 13));
    const unsigned char* BpB = (const unsigned char*)(Bp + ((size_t)bz * aBatch << 13));
    float* C = (float*)Cv + (EPI == 4 ? (size_t)bz * cBatch : 0);

    f32x4 acc[2][2];
    #pragma unroll
    for (int i = 0; i < 2; i++)
        #pragma unroll
        for (int j = 0; j < 2; j++) {
            f32x4 z = {0.f, 0.f, 0.f, 0.f};
            acc[i][j] = z;
        }

    const int nsteps = K >> 5;
    const size_t offA = ((size_t)(bx >> 1) * nsteps << 14) + ((size_t)(bx & 1) << 13);
    const size_t offB = ((size_t)(by >> 1) * nsteps << 14) + ((size_t)(by & 1) << 13);
    {
        #pragma unroll
        for (int i = 0; i < 2; i++) {
            int chunk = (i << 2) | wid;
            __builtin_amdgcn_global_load_lds((GAS_cv*)(ApB + offA + chunk * 1024 + lane * 16),
                (LAS_v*)((unsigned char*)Asl[0] + chunk * 1024), 16, 0, 0);
            __builtin_amdgcn_global_load_lds((GAS_cv*)(BpB + offB + chunk * 1024 + lane * 16),
                (LAS_v*)((unsigned char*)Bsl[0] + chunk * 1024), 16, 0, 0);
        }
    }
    for (int ks = 0; ks < nsteps; ks++) {
        const int kn = (ks + 1 < nsteps) ? ks + 1 : nsteps - 1;   // clamp: vmcnt const
        RAW_BAR();
        {
            const unsigned char* imgA = ApB + offA + ((size_t)kn << 14);
            const unsigned char* imgB = BpB + offB + ((size_t)kn << 14);
            #pragma unroll
            for (int i = 0; i < 2; i++) {
                int chunk = (i << 2) | wid;
                __builtin_amdgcn_global_load_lds((GAS_cv*)(imgA + chunk * 1024 + lane * 16),
                    (LAS_v*)((unsigned char*)Asl[(ks + 1) & 1] + chunk * 1024), 16, 0, 0);
                __builtin_amdgcn_global_load_lds((GAS_cv*)(imgB + chunk * 1024 + lane * 16),
                    (LAS_v*)((unsigned char*)Bsl[(ks + 1) & 1] + chunk * 1024), 16, 0, 0);
            }
        }
        asm volatile("s_waitcnt vmcnt(4)" ::: "memory");
        __builtin_amdgcn_sched_barrier(0);
        RAW_BAR();
        const int fr = lane & 15, kg = lane >> 4;
        bf16x8 ah[2], al[2], bh[2], bl[2];
        #pragma unroll
        for (int m = 0; m < 2; m++) {
            int r = wr * 32 + m * 16 + fr;
            int swz = (r & 7) << 4;
            const unsigned char* base = (const unsigned char*)Asl[ks & 1] + r * 128;
            ah[m] = *(const bf16x8*)(base + ((16 * kg) ^ swz));
            al[m] = *(const bf16x8*)(base + ((64 + 16 * kg) ^ swz));
        }
        #pragma unroll
        for (int n = 0; n < 2; n++) {
            int r = wc * 32 + n * 16 + fr;
            int swz = (r & 7) << 4;
            const unsigned char* base = (const unsigned char*)Bsl[ks & 1] + r * 128;
            bh[n] = *(const bf16x8*)(base + ((16 * kg) ^ swz));
            bl[n] = *(const bf16x8*)(base + ((64 + 16 * kg) ^ swz));
        }
        #pragma unroll
        for (int m = 0; m < 2; m++)
            #pragma unroll
            for (int n = 0; n < 2; n++) {
                acc[m][n] = __builtin_amdgcn_mfma_f32_16x16x32_bf16(ah[m], bh[n], acc[m][n], 0, 0, 0);
                acc[m][n] = __builtin_amdgcn_mfma_f32_16x16x32_bf16(ah[m], bl[n], acc[m][n], 0, 0, 0);
                acc[m][n] = __builtin_amdgcn_mfma_f32_16x16x32_bf16(al[m], bh[n], acc[m][n], 0, 0, 0);
            }
    }

    const int fr = lane & 15, fq = lane >> 4;
    const int m0 = bx * 64, n0 = by * 64;
    #pragma unroll
    for (int m = 0; m < 2; m++) {
        #pragma unroll
        for (int rr = 0; rr < 4; rr++) {
            int row = m0 + wr * 32 + m * 16 + fq * 4 + rr;
            if (row >= M) continue;
            #pragma unroll
            for (int n = 0; n < 2; n++) {
                int col = n0 + wc * 32 + n * 16 + fr;
                float v = acc[m][n][rr];
                size_t ci = (size_t)row * ldc + col;
                if (EPI == 1) {
                    C[ci] = v + bias[col] + res[ci];
                } else if (EPI == 4) {
                    C[ci] = v;
                } else if (EPI == 5) {
                    v += bias[col];
                    v = 0.5f * v * (1.0f + erff(v * 0.70710678118654752f));
                    unsigned short hh = f2bf(v);
                    unsigned short ll = f2bf(v - bf2f(hh));
                    unsigned char* img = (unsigned char*)Cv +
                        (((size_t)(row >> 7) * (ldc >> 5) + (col >> 5)) << 14);
                    int r2 = row & 127, swz2 = (r2 & 7) << 4, kc = col & 31;
                    *(unsigned short*)(img + r2 * 128 + ((2 * kc) ^ swz2)) = hh;
                    *(unsigned short*)(img + r2 * 128 + ((64 + 2 * kc) ^ swz2)) = ll;
                } else { // 6: qkv scatter (head = (col>>6)-12 for K, -24 for V)
                    float v2 = v + bias[col];
                    if (col < 768) {
                        ((float*)Cv)[(size_t)row * 768 + col] = v2;
                    } else {
                        int b_local = row / SEQ;
                        int s = row - b_local * SEQ;
                        int dloc = col & 63;
                        int kt = s >> 6, r2 = s & 63;
                        unsigned short hh = f2bf(v2);
                        unsigned short ll = f2bf(v2 - bf2f(hh));
                        if (col < 1536) {
                            int hh_i = (col >> 6) - 12;
                            size_t imgi = (((size_t)b_local * NHEADS + hh_i) * NKT + kt) << 14;
                            unsigned char* img = (unsigned char*)Kimg + imgi;
                            int off = (2 * dloc) ^ ((r2 & 7) << 4);
                            *(unsigned short*)(img + r2 * 256 + off) = hh;
                            *(unsigned short*)(img + r2 * 256 + 128 + off) = ll;
                        } else {
                            int hh_i = (col >> 6) - 24;
                            size_t imgi = (((size_t)b_local * NHEADS + hh_i) * NKT + kt) << 14;
                            unsigned char* img = (unsigned char*)Vimg + imgi;
                            int off = (2 * r2) ^ ((dloc & 7) << 4);
                            *(unsigned short*)(img + dloc * 256 + off) = hh;
                            *(unsigned short*)(img + dloc * 256 + 128 + off) = ll;
                        }
                    }
                }
            }
        }
    }
}

// ---------------- MFMA flash attention: K/Vt images in, O images out ----------------
__global__ __launch_bounds__(256) void attn_glds(const float* __restrict__ Qb,
        const unsigned short* __restrict__ Kimg, const unsigned short* __restrict__ Vimg,
        unsigned short* __restrict__ attimg, int row0) {
    int bx, by, bz;
    xcd_map(bx, by, bz);
    const int b = bz, h = by, q0 = bx * 64;
    const int t = threadIdx.x;
    const int lane = t & 63, wid = t >> 6;
    const int fr = lane & 15, kg = lane >> 4;
    __shared__ unsigned short Khl[64 * 128];
    __shared__ unsigned short Vt[64 * 128];
    __shared__ unsigned char Pbuf[16384];
    unsigned char* KhlB = (unsigned char*)Khl;
    unsigned char* VtB = (unsigned char*)Vt;
    unsigned char* PwB = Pbuf + wid * 4096;
    const unsigned char* KiB = (const unsigned char*)Kimg + (((size_t)b * NHEADS + h) * NKT << 14);
    const unsigned char* ViB = (const unsigned char*)Vimg + (((size_t)b * NHEADS + h) * NKT << 14);

    bf16x8 qh[2], qlo[2];
    {
        int qrow = q0 + wid * 16 + fr; qrow = qrow < SEQ ? qrow : SEQ - 1;
        const float* qbase = Qb + ((size_t)b * SEQ + qrow) * CDIM + h * DHEAD;
        #pragma unroll
        for (int ds = 0; ds < 2; ds++) {
            float tmp[8];
            *(float4*)(tmp)     = *(const float4*)(qbase + ds * 32 + kg * 8);
            *(float4*)(tmp + 4) = *(const float4*)(qbase + ds * 32 + kg * 8 + 4);
            #pragma unroll
            for (int j = 0; j < 8; j++) {
                unsigned short hh = f2bf(tmp[j]);
                qh[ds][j]  = (short)hh;
                qlo[ds][j] = (short)f2bf(tmp[j] - bf2f(hh));
            }
        }
    }

    f32x4 acc_o[4];
    #pragma unroll
    for (int i = 0; i < 4; i++) { f32x4 z = {0.f,0.f,0.f,0.f}; acc_o[i] = z; }
    float m_run[4] = {-1e30f, -1e30f, -1e30f, -1e30f};
    float l_run[4] = {0.f, 0.f, 0.f, 0.f};

    for (int kt = 0; kt < NKT; kt++) {
        const int c0 = kt * 64;
        __syncthreads();
        {
            const unsigned char* ki = KiB + ((size_t)kt << 14);
            const unsigned char* vi = ViB + ((size_t)kt << 14);
            #pragma unroll
            for (int i = 0; i < 4; i++) {
                int chunk = (i << 2) | wid;
                __builtin_amdgcn_global_load_lds((GAS_cv*)(ki + chunk * 1024 + lane * 16),
                    (LAS_v*)(KhlB + chunk * 1024), 16, 0, 0);
                __builtin_amdgcn_global_load_lds((GAS_cv*)(vi + chunk * 1024 + lane * 16),
                    (LAS_v*)(VtB + chunk * 1024), 16, 0, 0);
            }
        }
        __syncthreads();
        f32x4 s[4];
        #pragma unroll
        for (int i = 0; i < 4; i++) { f32x4 z = {0.f,0.f,0.f,0.f}; s[i] = z; }
        #pragma unroll
        for (int ds = 0; ds < 2; ds++) {
            #pragma unroll
            for (int n = 0; n < 4; n++) {
                int r = n * 16 + fr;
                int swz = (r & 7) << 4;
                const unsigned char* rb = KhlB + r * 256;
                bf16x8 kh = *(const bf16x8*)(rb + ((ds * 64 + kg * 16) ^ swz));
                bf16x8 kl = *(const bf16x8*)(rb + 128 + ((ds * 64 + kg * 16) ^ swz));
                s[n] = __builtin_amdgcn_mfma_f32_16x16x32_bf16(qh[ds], kh, s[n], 0, 0, 0);
                s[n] = __builtin_amdgcn_mfma_f32_16x16x32_bf16(qh[ds], kl, s[n], 0, 0, 0);
                s[n] = __builtin_amdgcn_mfma_f32_16x16x32_bf16(qlo[ds], kh, s[n], 0, 0, 0);
            }
        }
        float p[4][4];
        #pragma unroll
        for (int n = 0; n < 4; n++) {
            int kcol = c0 + n * 16 + fr;
            #pragma unroll
            for (int r = 0; r < 4; r++) {
                float sv = s[n][r] * 0.125f;
                if (kcol >= SEQ) sv = -1e30f;
                p[n][r] = sv;
            }
        }
        float corr[4];
        #pragma unroll
        for (int r = 0; r < 4; r++) {
            float mx = fmaxf(fmaxf(p[0][r], p[1][r]), fmaxf(p[2][r], p[3][r]));
            mx = fmaxf(mx, __shfl_xor(mx, 1));
            mx = fmaxf(mx, __shfl_xor(mx, 2));
            mx = fmaxf(mx, __shfl_xor(mx, 4));
            mx = fmaxf(mx, __shfl_xor(mx, 8));
            float mnew = fmaxf(m_run[r], mx);
            corr[r] = __expf(m_run[r] - mnew);
            m_run[r] = mnew;
            float ls = 0.f;
            #pragma unroll
            for (int n = 0; n < 4; n++) {
                p[n][r] = __expf(p[n][r] - mnew);
                ls += p[n][r];
            }
            ls += __shfl_xor(ls, 1);
            ls += __shfl_xor(ls, 2);
            ls += __shfl_xor(ls, 4);
            ls += __shfl_xor(ls, 8);
            l_run[r] = l_run[r] * corr[r] + ls;
        }
        #pragma unroll
        for (int nd = 0; nd < 4; nd++)
            #pragma unroll
            for (int r = 0; r < 4; r++)
                acc_o[nd][r] *= corr[r];
        {
            int qb = (lane >> 4) * 4;
            #pragma unroll
            for (int n = 0; n < 4; n++) {
                int kcol = n * 16 + fr;
                #pragma unroll
                for (int r = 0; r < 4; r++) {
                    int qq = qb + r;
                    unsigned short ph = f2bf(p[n][r]);
                    unsigned short pl = f2bf(p[n][r] - bf2f(ph));
                    int off = (kcol * 2) ^ ((qq & 7) << 4);
                    *(unsigned short*)(PwB + qq * 256 + off) = ph;
                    *(unsigned short*)(PwB + qq * 256 + 128 + off) = pl;
                }
            }
        }
        #pragma unroll
        for (int ks = 0; ks < 2; ks++) {
            int swzp = (fr & 7) << 4;
            bf16x8 pah = *(const bf16x8*)(PwB + fr * 256 + ((ks * 64 + kg * 16) ^ swzp));
            bf16x8 pal = *(const bf16x8*)(PwB + fr * 256 + 128 + ((ks * 64 + kg * 16) ^ swzp));
            #pragma unroll
            for (int nd = 0; nd < 4; nd++) {
                int rv = nd * 16 + fr;
                int swzv = (rv & 7) << 4;
                const unsigned char* rb = VtB + rv * 256;
                bf16x8 vh = *(const bf16x8*)(rb + ((ks * 64 + kg * 16) ^ swzv));
                bf16x8 vl = *(const bf16x8*)(rb + 128 + ((ks * 64 + kg * 16) ^ swzv));
                acc_o[nd] = __builtin_amdgcn_mfma_f32_16x16x32_bf16(pah, vh, acc_o[nd], 0, 0, 0);
                acc_o[nd] = __builtin_amdgcn_mfma_f32_16x16x32_bf16(pah, vl, acc_o[nd], 0, 0, 0);
                acc_o[nd] = __builtin_amdgcn_mfma_f32_16x16x32_bf16(pal, vh, acc_o[nd], 0, 0, 0);
            }
        }
    }
    // epilogue: O -> plane images (global row index)
    #pragma unroll
    for (int r = 0; r < 4; r++) {
        int q = q0 + wid * 16 + (lane >> 4) * 4 + r;
        if (q >= SEQ) continue;
        float inv = 1.f / l_run[r];
        int grow = row0 + b * SEQ + q;
        int r2 = grow & 127;
        size_t ibase = (size_t)(grow >> 7) * 24;
        int swz = (r2 & 7) << 4;
        #pragma unroll
        for (int nd = 0; nd < 4; nd++) {
            int col = h * DHEAD + nd * 16 + fr;
            float v = acc_o[nd][r] * inv;
            unsigned short hh = f2bf(v);
            unsigned short ll = f2bf(v - bf2f(hh));
            unsigned char* ip = (unsigned char*)attimg + ((ibase + (col >> 5)) << 14) + r2 * 128;
            int kc = col & 31;
            *(unsigned short*)(ip + ((2 * kc) ^ swz)) = hh;
            *(unsigned short*)(ip + ((64 + 2 * kc) ^ swz)) = ll;
        }
    }
}

// ---------------- row max of symmetrized sim (excluding diagonal) ----------------
__global__ __launch_bounds__(64) void rowmax_kernel(const float* __restrict__ sim,
                                                    float* __restrict__ ms) {
    int row = blockIdx.x;
    int b = row / NIMG, n = row % NIMG;
    const float* sb = sim + (size_t)b * NIMG * NIMG;
    int lane = threadIdx.x;
    float mx = -1e30f;
    #pragma unroll
    for (int i = 0; i < NIMG / 64; i++) {
        int m = lane + i * 64;
        if (m != n) {
            float v = 0.5f * (sb[(size_t)n * NIMG + m] + sb[(size_t)m * NIMG + n]);
            mx = fmaxf(mx, v);
        }
    }
    #pragma unroll
    for (int o = 32; o; o >>= 1) mx = fmaxf(mx, __shfl_down(mx, o));
    if (lane == 0) ms[row] = mx;
}

// ---------------- exact top-k selection with lax.top_k tie semantics ----------------
__global__ __launch_bounds__(576) void select_kernel(const float* __restrict__ ms,
        int* __restrict__ mergemask, int* __restrict__ keeppos) {
    __shared__ float v[NIMG];
    __shared__ int keepf[NIMG];
    int b = blockIdx.x;
    int n = threadIdx.x;
    v[n] = ms[b * NIMG + n];
    __syncthreads();
    float vn = v[n];
    int rank_desc = 0, rank_asc = 0;
    for (int m = 0; m < NIMG; m++) {
        float vm = v[m];
        int tie_lo = (vm == vn && m < n);
        rank_desc += (vm > vn) || tie_lo;
        rank_asc  += (vm < vn) || tie_lo;
    }
    int merge = rank_desc < NMERGE;
    int keep  = rank_asc  < NMERGE;
    mergemask[b * NIMG + n] = merge;
    keepf[n] = keep;
    __syncthreads();
    if (keep) {
        int pos = 0;
        for (int m = 0; m < n; m++) pos += keepf[m];
        keeppos[b * NIMG + n] = pos;
    } else {
        keeppos[b * NIMG + n] = -1;
    }
}

// ---------------- average of merged tokens (parallelized) ----------------
__global__ __launch_bounds__(256) void avg_kernel(const float* __restrict__ x2,
        const int* __restrict__ mask, float* __restrict__ avg) {
    __shared__ float4 red[8][33];
    int b = blockIdx.x, cc = blockIdx.y;
    int t = threadIdx.x;
    int rr = t >> 5, c4 = t & 31;
    int c = cc * 128 + c4 * 4;
    const int* mb = mask + b * NIMG;
    float4 s = make_float4(0.f, 0.f, 0.f, 0.f);
    for (int n = rr; n < NIMG; n += 8) {
        if (mb[n]) {
            float4 v = *(const float4*)(x2 + ((size_t)b * SEQ + 1 + n) * CDIM + c);
            s.x += v.x; s.y += v.y; s.z += v.z; s.w += v.w;
        }
    }
    red[rr][c4] = s;
    __syncthreads();
    if (rr == 0) {
        float4 tot = red[0][c4];
        #pragma unroll
        for (int i = 1; i < 8; i++) {
            float4 v = red[i][c4];
            tot.x += v.x; tot.y += v.y; tot.z += v.z; tot.w += v.w;
        }
        float sc1 = 1.f / (float)NMERGE, sc2 = 1.f / (float)(NIMG - NMERGE);
        tot.x = (tot.x * sc1) * sc2; tot.y = (tot.y * sc1) * sc2;
        tot.z = (tot.z * sc1) * sc2; tot.w = (tot.w * sc1) * sc2;
        *(float4*)(avg + (size_t)b * CDIM + c) = tot;
    }
}

// ---------------- assemble output ----------------
__global__ __launch_bounds__(192) void assemble_kernel(const float* __restrict__ x2,
        const int* __restrict__ keeppos, const float* __restrict__ avg,
        float* __restrict__ out) {
    int g = blockIdx.x;
    int b = g / SEQ, s_ = g % SEQ;
    int t = threadIdx.x;
    const float4* src = (const float4*)(x2 + (size_t)g * CDIM);
    if (s_ == 0) {
        float4* dst = (float4*)(out + (size_t)b * 289 * CDIM);
        dst[t] = src[t];
    } else {
        int n = s_ - 1;
        int pos = keeppos[b * NIMG + n];
        if (pos < 0) return;
        const float4* av = (const float4*)(avg + (size_t)b * CDIM);
        float4 v = src[t], a = av[t];
        v.x += a.x; v.y += a.y; v.z += a.z; v.w += a.w;
        float4* dst = (float4*)(out + ((size_t)b * 289 + 1 + pos) * CDIM);
        dst[t] = v;
    }
}

extern "C" void kernel_launch(void* const* d_in, const int* in_sizes, int n_in,
                              void* d_out, int out_size, void* d_ws, size_t ws_size,
                              hipStream_t stream) {
    const float* x      = (const float*)d_in[0];
    const float* qkv_w  = (const float*)d_in[1];
    const float* qkv_b  = (const float*)d_in[2];
    const float* proj_w = (const float*)d_in[3];
    const float* proj_b = (const float*)d_in[4];
    const float* ln1_g  = (const float*)d_in[5];
    const float* ln1_b  = (const float*)d_in[6];
    const float* ln2_g  = (const float*)d_in[7];
    const float* ln2_b  = (const float*)d_in[8];
    const float* fc1_w  = (const float*)d_in[9];
    const float* fc1_b  = (const float*)d_in[10];
    const float* fc2_w  = (const float*)d_in[11];
    const float* fc2_b  = (const float*)d_in[12];

    if (ws_size < NEED_BYTES) return;

    float* ws   = (float*)d_ws;
    float* bh   = ws + O_BH;
    float* ba   = ws + O_BA;
    float* bq   = ws + O_BQ;
    float* qbuf = ws + O_BQ;
    unsigned short* kimg = (unsigned short*)(ws + O_KIMG);
    unsigned short* vimg = (unsigned short*)(ws + O_VIMG);
    float* ms   = ws + O_MS;
    int*   mask = (int*)(ws + O_MASK);
    int*   pos  = (int*)(ws + O_POS);
    float* avg  = ws + O_AVG;
    float* outp = (float*)d_out;

    unsigned short* himg   = (unsigned short*)bh;
    unsigned short* attimg = (unsigned short*)ba;
    unsigned short* h2img  = (unsigned short*)ba;
    unsigned short* xnimg  = (unsigned short*)ba;
    unsigned short* fopl   = (unsigned short*)bq;

    unsigned short* qkvp  = (unsigned short*)(outp + OW_QKV);
    unsigned short* fc1p  = (unsigned short*)(outp + OW_FC1);
    unsigned short* fc2p  = (unsigned short*)(outp + OW_FC2);
    unsigned short* projp = (unsigned short*)(outp + OW_PROJ);

    // 0. split weights; zero V-image scratch
    wsplit_kernel<<<18 * 24, 256, 0, stream>>>(qkv_w, qkvp, 24, CDIM);
    wsplit_kernel<<<24 * 24, 256, 0, stream>>>(fc1_w, fc1p, 24, CDIM);
    wsplit_kernel<<<6 * 96, 256, 0, stream>>>(fc2_w, fc2p, 96, 3072);
    wsplit_kernel<<<6 * 24, 256, 0, stream>>>(proj_w, projp, 24, CDIM);
    hipMemsetAsync(vimg, 0, SZ_IMG * 4, stream);

    // 1. h = LN1(x) -> group-padded plane images in BH
    ln_split<<<MTOK, 256, 0, stream>>>(x, ln1_g, ln1_b, himg, MGRP, 37);

    // 2. per-group qkv (dual-glds) + attention -> att images in BA
    for (int g = 0; g < NGROUP; g++) {
        gemm_ppx<6><<<dim3(73, 36), 256, 0, stream>>>(
            himg + (size_t)g * 37 * 24 * 8192, qkvp, (void*)qbuf, 3 * CDIM,
            qkv_b, nullptr, MGRP, 3 * CDIM, CDIM, 0, 0, kimg, vimg);
        attn_glds<<<dim3(NKT, NHEADS, GB), 256, 0, stream>>>(
            qbuf, kimg, vimg, attimg, g * MGRP);
    }

    // 3. x1 = x + att @ proj_w^T + proj_b (dual-glds) -> BH fp32
    gemm_ppx<1><<<dim3((MTOK + 63) / 64, 12), 256, 0, stream>>>(
        attimg, projp, (void*)bh, CDIM, proj_b, x, MTOK, CDIM, CDIM,
        0, 0, nullptr, nullptr);

    // 4. h2 = LN2(x1) -> global plane images in BA
    ln_split<<<MTOK, 256, 0, stream>>>(bh, ln2_g, ln2_b, h2img, MTOK, 145);

    // 5. MLP chunks: fc1 (gelu -> fc1o images), fc2 (+res in-place BH)
    for (int c0 = 0; c0 < MTOK; c0 += MLPCH) {
        int mc = (MTOK - c0 < MLPCH) ? (MTOK - c0) : MLPCH;
        float* x1c = bh + (size_t)c0 * CDIM;
        gemm_ppx<5><<<dim3((mc + 63) / 64, 48), 256, 0, stream>>>(
            h2img + (size_t)(c0 >> 7) * 24 * 8192, fc1p, (void*)fopl, 3072,
            fc1_b, nullptr, mc, 3072, CDIM, 0, 0, nullptr, nullptr);
        gemm_ppx<1><<<dim3((mc + 63) / 64, 12), 256, 0, stream>>>(
            fopl, fc2p, (void*)x1c, CDIM, fc2_b, x1c,
            mc, CDIM, 3072, 0, 0, nullptr, nullptr);
    }

    // 6-8. two batch-halves: xn images -> batched sim -> rowmax
    for (int hf = 0; hf < 2; hf++) {
        xn_split<<<16 * NIMG, 256, 0, stream>>>(bh, xnimg, hf * 16);
        gemm_ppx<4><<<dim3(9, 9, 16), 256, 0, stream>>>(
            xnimg, xnimg, (void*)bq, NIMG, nullptr, nullptr,
            NIMG, NIMG, CDIM, 5 * 24, (long long)NIMG * NIMG, nullptr, nullptr);
        rowmax_kernel<<<16 * NIMG, 64, 0, stream>>>(bq, ms + (size_t)hf * 16 * NIMG);
    }

    // 9-11. selection, merged average, assemble
    select_kernel<<<NBATCH, NIMG, 0, stream>>>(ms, mask, pos);
    avg_kernel<<<dim3(NBATCH, 6), 256, 0, stream>>>(bh, mask, avg);
    assemble_kernel<<<MTOK, 192, 0, stream>>>(bh, pos, avg, outp);
}

// Round 21
// 1653.334 us; speedup vs baseline: 1.1285x; 1.0411x over previous
//
#include <hip/hip_runtime.h>
#include <math.h>

#define CDIM 768
#define NHEADS 12
#define DHEAD 64
#define SEQ 577
#define NBATCH 32
#define MTOK (NBATCH*SEQ)      // 18464
#define NIMG 576
#define NMERGE 288
#define GB 8                   // batches per qkv group
#define NGROUP (NBATCH/GB)     // 4
#define MGRP (GB*SEQ)          // 4616 rows per group
#define MLPCH 3456             // MLP chunk rows (27x128)
#define NKT 10                 // k-tiles per (b,h) in attention

// ---- workspace layout (float offsets), peak ~161.2 MB ----
#define SZ_BH   ((size_t)4*37*24*4096)           // h images / x1/x2 fp32
#define O_BH    ((size_t)0)
#define O_BA    (SZ_BH)                          // att images / h2 images / xn images
#define SZ_BA   ((size_t)145*24*4096)
#define O_BQ    (O_BA + SZ_BA)                   // Q rows + K/V images / fc1o images / sim half
#define SZ_Q    ((size_t)MGRP*CDIM)
#define SZ_IMG  ((size_t)GB*NHEADS*NKT*4096)
#define O_KIMG  (O_BQ + SZ_Q)
#define O_VIMG  (O_KIMG + SZ_IMG)
#define O_SM    (O_VIMG + SZ_IMG)
#define O_MS    (O_SM)
#define O_MASK  (O_SM + (size_t)NBATCH*NIMG)
#define O_POS   (O_MASK + (size_t)NBATCH*NIMG)
#define O_AVG   (O_POS + (size_t)NBATCH*NIMG)
#define O_END   (O_AVG + (size_t)NBATCH*CDIM)
#define NEED_BYTES (O_END * 4)

// ---- weight-plane scratch inside d_out ----
#define OW_QKV  ((size_t)0)
#define OW_FC1  ((size_t)1769472)
#define OW_FC2  ((size_t)4128768)
#define OW_PROJ ((size_t)6488064)

typedef __attribute__((ext_vector_type(8))) short bf16x8;
typedef __attribute__((ext_vector_type(4))) float f32x4;
typedef __attribute__((address_space(1))) const void GAS_cv;
typedef __attribute__((address_space(3))) void LAS_v;

#define RAW_BAR() do { asm volatile("" ::: "memory"); \
    __builtin_amdgcn_s_barrier(); asm volatile("" ::: "memory"); } while (0)

__device__ __forceinline__ unsigned short f2bf(float f) {
    unsigned int u = __float_as_uint(f);
    u += 0x7fff + ((u >> 16) & 1);           // RNE
    return (unsigned short)(u >> 16);
}
__device__ __forceinline__ float bf2f(unsigned short h) {
    return __uint_as_float(((unsigned int)h) << 16);
}

// ---- bijective XCD chunk remaps (m204) ----
__device__ __forceinline__ void xcd_map(int& bx, int& by, int& bz) {
    int gx = gridDim.x, gy = gridDim.y;
    int nwg = gx * gy * gridDim.z;
    int orig = blockIdx.x + gx * (blockIdx.y + gy * blockIdx.z);
    int q = nwg >> 3, r = nwg & 7;
    int xcd = orig & 7, pos = orig >> 3;
    int wg = (xcd < r ? xcd * (q + 1) : r * (q + 1) + (xcd - r) * q) + pos;
    bx = wg % gx;
    int t2 = wg / gx;
    by = t2 % gy;
    bz = t2 / gy;
}
// plain by-fastest (round-18 proven): consecutive blocks share the A panel.
__device__ __forceinline__ void xcd_map_nf(int& bx, int& by, int& bz) {
    int gx = gridDim.x, gy = gridDim.y;
    int nwg = gx * gy * gridDim.z;
    int orig = blockIdx.x + gx * (blockIdx.y + gy * blockIdx.z);
    int q = nwg >> 3, r = nwg & 7;
    int xcd = orig & 7, pos = orig >> 3;
    int wg = (xcd < r ? xcd * (q + 1) : r * (q + 1) + (xcd - r) * q) + pos;
    by = wg % gy;
    int t2 = wg / gy;
    bx = t2 % gx;
    bz = t2 / gx;
}

// ---------------- block reduce (256 threads) ----------------
__device__ __forceinline__ float blk_sum256(float v, float* red) {
    #pragma unroll
    for (int o = 32; o; o >>= 1) v += __shfl_down(v, o);
    if ((threadIdx.x & 63) == 0) red[threadIdx.x >> 6] = v;
    __syncthreads();
    float tot = red[0] + red[1] + red[2] + red[3];
    __syncthreads();
    return tot;
}

// ---------------- LayerNorm -> bf16 hi/lo plane IMAGES ----------------
__global__ __launch_bounds__(256) void ln_split(const float* __restrict__ x,
        const float* __restrict__ g, const float* __restrict__ b,
        unsigned short* __restrict__ img, int rows_per_grp, int imgrows_per_grp) {
    __shared__ float red[4];
    int row = blockIdx.x;
    const float* xr = x + (size_t)row * CDIM;
    int t = threadIdx.x;
    float v0 = xr[t], v1 = xr[t + 256], v2 = xr[t + 512];
    float mu = blk_sum256(v0 + v1 + v2, red) * (1.f / CDIM);
    float d0 = v0 - mu, d1 = v1 - mu, d2 = v2 - mu;
    float var = blk_sum256(d0 * d0 + d1 * d1 + d2 * d2, red) * (1.f / CDIM);
    float e = var + 1e-5f;
    float rs = rsqrtf(e);
    rs = rs * (1.5f - 0.5f * e * rs * rs);
    float vals[3] = {d0 * rs * g[t] + b[t],
                     d1 * rs * g[t + 256] + b[t + 256],
                     d2 * rs * g[t + 512] + b[t + 512]};
    int grp = row / rows_per_grp;
    int local = row - grp * rows_per_grp;
    int r2 = local & 127;
    size_t ibase = ((size_t)grp * imgrows_per_grp + (local >> 7)) * 24;
    int swz = (r2 & 7) << 4;
    #pragma unroll
    for (int cc = 0; cc < 3; cc++) {
        int col = t + cc * 256;
        int ks = col >> 5, kc = col & 31;
        unsigned char* ip = (unsigned char*)img + ((ibase + ks) << 14) + r2 * 128;
        float v = vals[cc];
        unsigned short hh = f2bf(v);
        unsigned short ll = f2bf(v - bf2f(hh));
        *(unsigned short*)(ip + ((2 * kc) ^ swz)) = hh;
        *(unsigned short*)(ip + ((64 + 2 * kc) ^ swz)) = ll;
    }
}

// ---------------- normalize img tokens -> plane IMAGES (per batch-half) ------
__global__ __launch_bounds__(256) void xn_split(const float* __restrict__ x2,
        unsigned short* __restrict__ img, int b0) {
    __shared__ float red[4];
    int tok = blockIdx.x;
    int bl = tok / NIMG, n = tok % NIMG;
    const float* xr = x2 + ((size_t)(b0 + bl) * SEQ + 1 + n) * CDIM;
    int t = threadIdx.x;
    float v0 = xr[t], v1 = xr[t + 256], v2 = xr[t + 512];
    float ss = blk_sum256(v0 * v0 + v1 * v1 + v2 * v2, red);
    float nrm = fmaxf(sqrtf(ss), 1e-12f);
    float inv = 1.f / nrm;
    float vals[3] = {v0 * inv, v1 * inv, v2 * inv};
    int r2 = n & 127;
    size_t ibase = ((size_t)bl * 5 + (n >> 7)) * 24;
    int swz = (r2 & 7) << 4;
    #pragma unroll
    for (int cc = 0; cc < 3; cc++) {
        int col = t + cc * 256;
        int ks = col >> 5, kc = col & 31;
        unsigned char* ip = (unsigned char*)img + ((ibase + ks) << 14) + r2 * 128;
        float v = vals[cc];
        unsigned short hh = f2bf(v);
        unsigned short ll = f2bf(v - bf2f(hh));
        *(unsigned short*)(ip + ((2 * kc) ^ swz)) = hh;
        *(unsigned short*)(ip + ((64 + 2 * kc) ^ swz)) = ll;
    }
}

// ---------------- weight split: fp32 -> bf16 hi/lo LDS-image planes ----------------
__global__ __launch_bounds__(256) void wsplit_kernel(const float* __restrict__ w,
        unsigned short* __restrict__ wp, int nksteps, int ldw) {
    int bid = blockIdx.x;
    int nt = bid / nksteps, ks = bid % nksteps;
    int t = threadIdx.x;
    int srow = t >> 3, sj = t & 7;
    unsigned short* img = wp + ((size_t)bid << 13);
    #pragma unroll
    for (int i = 0; i < 4; i++) {
        int r = srow + i * 32;
        float4 v = *(const float4*)(w + (size_t)(nt * 128 + r) * ldw + ks * 32 + sj * 4);
        unsigned short h0 = f2bf(v.x), h1 = f2bf(v.y), h2 = f2bf(v.z), h3 = f2bf(v.w);
        ushort4 hv = make_ushort4(h0, h1, h2, h3);
        ushort4 lv = make_ushort4(f2bf(v.x - bf2f(h0)), f2bf(v.y - bf2f(h1)),
                                  f2bf(v.z - bf2f(h2)), f2bf(v.w - bf2f(h3)));
        int swz = (r & 7) << 4;
        int ohi = ((8 * sj) ^ swz) >> 1;
        int olo = ((64 + 8 * sj) ^ swz) >> 1;
        *(ushort4*)&img[r * 64 + ohi] = hv;
        *(ushort4*)&img[r * 64 + olo] = lv;
    }
}

// ---------------- shared epilogue (per-element) ----------------
template<int EPI>
__device__ __forceinline__ void epi_store(float v, int row, int col, int ldc,
        void* Cv, float* C, const float* bias, const float* res,
        unsigned short* Kimg, unsigned short* Vimg) {
    size_t ci = (size_t)row * ldc + col;
    if (EPI == 1) {
        C[ci] = v + bias[col] + res[ci];
    } else if (EPI == 4) {
        C[ci] = v;
    } else if (EPI == 5) {
        v += bias[col];
        v = 0.5f * v * (1.0f + erff(v * 0.70710678118654752f));
        unsigned short hh = f2bf(v);
        unsigned short ll = f2bf(v - bf2f(hh));
        unsigned char* img = (unsigned char*)Cv +
            (((size_t)(row >> 7) * (ldc >> 5) + (col >> 5)) << 14);
        int r2 = row & 127, swz2 = (r2 & 7) << 4, kc = col & 31;
        *(unsigned short*)(img + r2 * 128 + ((2 * kc) ^ swz2)) = hh;
        *(unsigned short*)(img + r2 * 128 + ((64 + 2 * kc) ^ swz2)) = ll;
    } else { // 6: qkv scatter (head = (col>>6)-12 for K, -24 for V)
        float v2 = v + bias[col];
        if (col < 768) {
            ((float*)Cv)[(size_t)row * 768 + col] = v2;
        } else {
            int b_local = row / SEQ;
            int s = row - b_local * SEQ;
            int dloc = col & 63;
            int kt = s >> 6, r2 = s & 63;
            unsigned short hh = f2bf(v2);
            unsigned short ll = f2bf(v2 - bf2f(hh));
            if (col < 1536) {
                int hh_i = (col >> 6) - 12;
                size_t imgi = (((size_t)b_local * NHEADS + hh_i) * NKT + kt) << 14;
                unsigned char* img = (unsigned char*)Kimg + imgi;
                int off = (2 * dloc) ^ ((r2 & 7) << 4);
                *(unsigned short*)(img + r2 * 256 + off) = hh;
                *(unsigned short*)(img + r2 * 256 + 128 + off) = ll;
            } else {
                int hh_i = (col >> 6) - 24;
                size_t imgi = (((size_t)b_local * NHEADS + hh_i) * NKT + kt) << 14;
                unsigned char* img = (unsigned char*)Vimg + imgi;
                int off = (2 * r2) ^ ((dloc & 7) << 4);
                *(unsigned short*)(img + dloc * 256 + off) = hh;
                *(unsigned short*)(img + dloc * 256 + 128 + off) = ll;
            }
        }
    }
}

// ---------------- GEMM 64x64, both operands images, 1-deep pipeline (round-18) ---
// EPI: 1 = +bias+res, 4 = plain fp32 (batched sim), 5 = gelu->images
template<int EPI>
__global__ __launch_bounds__(256)
void gemm_ppx(const unsigned short* __restrict__ Ap,
              const unsigned short* __restrict__ Bp,
              void* __restrict__ Cv, int ldc,
              const float* __restrict__ bias,
              const float* __restrict__ res,
              int M, int N, int K,
              long long aBatch, long long cBatch,
              unsigned short* __restrict__ Kimg,
              unsigned short* __restrict__ Vimg) {
    __shared__ unsigned short Asl[2][64 * 64];
    __shared__ unsigned short Bsl[2][64 * 64];
    int bx, by, bz;
    xcd_map_nf(bx, by, bz);
    const int t = threadIdx.x;
    const int lane = t & 63, wid = t >> 6;
    const int wr = wid >> 1, wc = wid & 1;
    const unsigned char* ApB = (const unsigned char*)(Ap + ((size_t)bz * aBatch << 13));
    const unsigned char* BpB = (const unsigned char*)(Bp + ((size_t)bz * aBatch << 13));
    float* C = (float*)Cv + (EPI == 4 ? (size_t)bz * cBatch : 0);

    f32x4 acc[2][2];
    #pragma unroll
    for (int i = 0; i < 2; i++)
        #pragma unroll
        for (int j = 0; j < 2; j++) {
            f32x4 z = {0.f, 0.f, 0.f, 0.f};
            acc[i][j] = z;
        }

    const int nsteps = K >> 5;
    const size_t offA = ((size_t)(bx >> 1) * nsteps << 14) + ((size_t)(bx & 1) << 13);
    const size_t offB = ((size_t)(by >> 1) * nsteps << 14) + ((size_t)(by & 1) << 13);
    {
        #pragma unroll
        for (int i = 0; i < 2; i++) {
            int chunk = (i << 2) | wid;
            __builtin_amdgcn_global_load_lds((GAS_cv*)(ApB + offA + chunk * 1024 + lane * 16),
                (LAS_v*)((unsigned char*)Asl[0] + chunk * 1024), 16, 0, 0);
            __builtin_amdgcn_global_load_lds((GAS_cv*)(BpB + offB + chunk * 1024 + lane * 16),
                (LAS_v*)((unsigned char*)Bsl[0] + chunk * 1024), 16, 0, 0);
        }
    }
    for (int ks = 0; ks < nsteps; ks++) {
        const int kn = (ks + 1 < nsteps) ? ks + 1 : nsteps - 1;
        RAW_BAR();
        {
            const unsigned char* imgA = ApB + offA + ((size_t)kn << 14);
            const unsigned char* imgB = BpB + offB + ((size_t)kn << 14);
            #pragma unroll
            for (int i = 0; i < 2; i++) {
                int chunk = (i << 2) | wid;
                __builtin_amdgcn_global_load_lds((GAS_cv*)(imgA + chunk * 1024 + lane * 16),
                    (LAS_v*)((unsigned char*)Asl[(ks + 1) & 1] + chunk * 1024), 16, 0, 0);
                __builtin_amdgcn_global_load_lds((GAS_cv*)(imgB + chunk * 1024 + lane * 16),
                    (LAS_v*)((unsigned char*)Bsl[(ks + 1) & 1] + chunk * 1024), 16, 0, 0);
            }
        }
        asm volatile("s_waitcnt vmcnt(4)" ::: "memory");
        __builtin_amdgcn_sched_barrier(0);
        RAW_BAR();
        const int fr = lane & 15, kg = lane >> 4;
        bf16x8 ah[2], al[2], bh[2], bl[2];
        #pragma unroll
        for (int m = 0; m < 2; m++) {
            int r = wr * 32 + m * 16 + fr;
            int swz = (r & 7) << 4;
            const unsigned char* base = (const unsigned char*)Asl[ks & 1] + r * 128;
            ah[m] = *(const bf16x8*)(base + ((16 * kg) ^ swz));
            al[m] = *(const bf16x8*)(base + ((64 + 16 * kg) ^ swz));
        }
        #pragma unroll
        for (int n = 0; n < 2; n++) {
            int r = wc * 32 + n * 16 + fr;
            int swz = (r & 7) << 4;
            const unsigned char* base = (const unsigned char*)Bsl[ks & 1] + r * 128;
            bh[n] = *(const bf16x8*)(base + ((16 * kg) ^ swz));
            bl[n] = *(const bf16x8*)(base + ((64 + 16 * kg) ^ swz));
        }
        #pragma unroll
        for (int m = 0; m < 2; m++)
            #pragma unroll
            for (int n = 0; n < 2; n++) {
                acc[m][n] = __builtin_amdgcn_mfma_f32_16x16x32_bf16(ah[m], bh[n], acc[m][n], 0, 0, 0);
                acc[m][n] = __builtin_amdgcn_mfma_f32_16x16x32_bf16(ah[m], bl[n], acc[m][n], 0, 0, 0);
                acc[m][n] = __builtin_amdgcn_mfma_f32_16x16x32_bf16(al[m], bh[n], acc[m][n], 0, 0, 0);
            }
    }

    const int fr = lane & 15, fq = lane >> 4;
    const int m0 = bx * 64, n0 = by * 64;
    #pragma unroll
    for (int m = 0; m < 2; m++) {
        #pragma unroll
        for (int rr = 0; rr < 4; rr++) {
            int row = m0 + wr * 32 + m * 16 + fq * 4 + rr;
            if (row >= M) continue;
            #pragma unroll
            for (int n = 0; n < 2; n++) {
                int col = n0 + wc * 32 + n * 16 + fr;
                epi_store<EPI>(acc[m][n][rr], row, col, ldc, Cv, C, bias, res, Kimg, Vimg);
            }
        }
    }
}

// ---------------- GEMM 128x64: 4 waves stacked, 24 MFMA/wave/step ----------------
// A tile = one full 16KB image per K-step (offA = bx*nsteps*16K); B = half-image.
// Per-thread 4 A-glds + 2 B-glds per step -> vmcnt(6). Same 1-deep/2-buffer
// barrier algebra as gemm_ppx; per-element K-walk identical -> bit-identical.
// EPI: 1 = +bias+res, 5 = gelu->images, 6 = qkv scatter
template<int EPI>
__global__ __launch_bounds__(256)
void gemm_ppx2(const unsigned short* __restrict__ Ap,
               const unsigned short* __restrict__ Bp,
               void* __restrict__ Cv, int ldc,
               const float* __restrict__ bias,
               const float* __restrict__ res,
               int M, int N, int K,
               unsigned short* __restrict__ Kimg,
               unsigned short* __restrict__ Vimg) {
    __shared__ unsigned short Asl[2][128 * 64];   // 32 KB
    __shared__ unsigned short Bsl[2][64 * 64];    // 16 KB
    int bx, by, bz;
    xcd_map_nf(bx, by, bz);
    const int t = threadIdx.x;
    const int lane = t & 63, wid = t >> 6;
    const unsigned char* ApB = (const unsigned char*)Ap;
    const unsigned char* BpB = (const unsigned char*)Bp;
    float* C = (float*)Cv;

    f32x4 acc[2][4];
    #pragma unroll
    for (int i = 0; i < 2; i++)
        #pragma unroll
        for (int j = 0; j < 4; j++) {
            f32x4 z = {0.f, 0.f, 0.f, 0.f};
            acc[i][j] = z;
        }

    const int nsteps = K >> 5;
    const size_t offA = (size_t)bx * nsteps << 14;
    const size_t offB = ((size_t)(by >> 1) * nsteps << 14) + ((size_t)(by & 1) << 13);
    {
        #pragma unroll
        for (int i = 0; i < 4; i++) {
            int chunk = (i << 2) | wid;        // 0..15: full A image
            __builtin_amdgcn_global_load_lds((GAS_cv*)(ApB + offA + chunk * 1024 + lane * 16),
                (LAS_v*)((unsigned char*)Asl[0] + chunk * 1024), 16, 0, 0);
        }
        #pragma unroll
        for (int i = 0; i < 2; i++) {
            int chunk = (i << 2) | wid;        // 0..7: B half-image
            __builtin_amdgcn_global_load_lds((GAS_cv*)(BpB + offB + chunk * 1024 + lane * 16),
                (LAS_v*)((unsigned char*)Bsl[0] + chunk * 1024), 16, 0, 0);
        }
    }
    for (int ks = 0; ks < nsteps; ks++) {
        const int kn = (ks + 1 < nsteps) ? ks + 1 : nsteps - 1;
        RAW_BAR();
        {
            const unsigned char* imgA = ApB + offA + ((size_t)kn << 14);
            const unsigned char* imgB = BpB + offB + ((size_t)kn << 14);
            #pragma unroll
            for (int i = 0; i < 4; i++) {
                int chunk = (i << 2) | wid;
                __builtin_amdgcn_global_load_lds((GAS_cv*)(imgA + chunk * 1024 + lane * 16),
                    (LAS_v*)((unsigned char*)Asl[(ks + 1) & 1] + chunk * 1024), 16, 0, 0);
            }
            #pragma unroll
            for (int i = 0; i < 2; i++) {
                int chunk = (i << 2) | wid;
                __builtin_amdgcn_global_load_lds((GAS_cv*)(imgB + chunk * 1024 + lane * 16),
                    (LAS_v*)((unsigned char*)Bsl[(ks + 1) & 1] + chunk * 1024), 16, 0, 0);
            }
        }
        asm volatile("s_waitcnt vmcnt(6)" ::: "memory");   // step-ks loads done; 6 newer in flight
        __builtin_amdgcn_sched_barrier(0);
        RAW_BAR();
        const int fr = lane & 15, kg = lane >> 4;
        bf16x8 ah[2], al[2], bh[4], bl[4];
        #pragma unroll
        for (int m = 0; m < 2; m++) {
            int r = wid * 32 + m * 16 + fr;    // 0..127
            int swz = (r & 7) << 4;
            const unsigned char* base = (const unsigned char*)Asl[ks & 1] + r * 128;
            ah[m] = *(const bf16x8*)(base + ((16 * kg) ^ swz));
            al[m] = *(const bf16x8*)(base + ((64 + 16 * kg) ^ swz));
        }
        #pragma unroll
        for (int n = 0; n < 4; n++) {
            int r = n * 16 + fr;               // 0..63
            int swz = (r & 7) << 4;
            const unsigned char* base = (const unsigned char*)Bsl[ks & 1] + r * 128;
            bh[n] = *(const bf16x8*)(base + ((16 * kg) ^ swz));
            bl[n] = *(const bf16x8*)(base + ((64 + 16 * kg) ^ swz));
        }
        #pragma unroll
        for (int m = 0; m < 2; m++)
            #pragma unroll
            for (int n = 0; n < 4; n++) {
                acc[m][n] = __builtin_amdgcn_mfma_f32_16x16x32_bf16(ah[m], bh[n], acc[m][n], 0, 0, 0);
                acc[m][n] = __builtin_amdgcn_mfma_f32_16x16x32_bf16(ah[m], bl[n], acc[m][n], 0, 0, 0);
                acc[m][n] = __builtin_amdgcn_mfma_f32_16x16x32_bf16(al[m], bh[n], acc[m][n], 0, 0, 0);
            }
    }

    const int fr = lane & 15, fq = lane >> 4;
    const int m0 = bx * 128, n0 = by * 64;
    #pragma unroll
    for (int m = 0; m < 2; m++) {
        #pragma unroll
        for (int rr = 0; rr < 4; rr++) {
            int row = m0 + wid * 32 + m * 16 + fq * 4 + rr;
            if (row >= M) continue;
            #pragma unroll
            for (int n = 0; n < 4; n++) {
                int col = n0 + n * 16 + fr;
                epi_store<EPI>(acc[m][n][rr], row, col, ldc, Cv, C, bias, res, Kimg, Vimg);
            }
        }
    }
}

// ---------------- MFMA flash attention: K/Vt images in, O images out ----------------
__global__ __launch_bounds__(256) void attn_glds(const float* __restrict__ Qb,
        const unsigned short* __restrict__ Kimg, const unsigned short* __restrict__ Vimg,
        unsigned short* __restrict__ attimg, int row0) {
    int bx, by, bz;
    xcd_map(bx, by, bz);
    const int b = bz, h = by, q0 = bx * 64;
    const int t = threadIdx.x;
    const int lane = t & 63, wid = t >> 6;
    const int fr = lane & 15, kg = lane >> 4;
    __shared__ unsigned short Khl[64 * 128];
    __shared__ unsigned short Vt[64 * 128];
    __shared__ unsigned char Pbuf[16384];
    unsigned char* KhlB = (unsigned char*)Khl;
    unsigned char* VtB = (unsigned char*)Vt;
    unsigned char* PwB = Pbuf + wid * 4096;
    const unsigned char* KiB = (const unsigned char*)Kimg + (((size_t)b * NHEADS + h) * NKT << 14);
    const unsigned char* ViB = (const unsigned char*)Vimg + (((size_t)b * NHEADS + h) * NKT << 14);

    bf16x8 qh[2], qlo[2];
    {
        int qrow = q0 + wid * 16 + fr; qrow = qrow < SEQ ? qrow : SEQ - 1;
        const float* qbase = Qb + ((size_t)b * SEQ + qrow) * CDIM + h * DHEAD;
        #pragma unroll
        for (int ds = 0; ds < 2; ds++) {
            float tmp[8];
            *(float4*)(tmp)     = *(const float4*)(qbase + ds * 32 + kg * 8);
            *(float4*)(tmp + 4) = *(const float4*)(qbase + ds * 32 + kg * 8 + 4);
            #pragma unroll
            for (int j = 0; j < 8; j++) {
                unsigned short hh = f2bf(tmp[j]);
                qh[ds][j]  = (short)hh;
                qlo[ds][j] = (short)f2bf(tmp[j] - bf2f(hh));
            }
        }
    }

    f32x4 acc_o[4];
    #pragma unroll
    for (int i = 0; i < 4; i++) { f32x4 z = {0.f,0.f,0.f,0.f}; acc_o[i] = z; }
    float m_run[4] = {-1e30f, -1e30f, -1e30f, -1e30f};
    float l_run[4] = {0.f, 0.f, 0.f, 0.f};

    for (int kt = 0; kt < NKT; kt++) {
        const int c0 = kt * 64;
        __syncthreads();
        {
            const unsigned char* ki = KiB + ((size_t)kt << 14);
            const unsigned char* vi = ViB + ((size_t)kt << 14);
            #pragma unroll
            for (int i = 0; i < 4; i++) {
                int chunk = (i << 2) | wid;
                __builtin_amdgcn_global_load_lds((GAS_cv*)(ki + chunk * 1024 + lane * 16),
                    (LAS_v*)(KhlB + chunk * 1024), 16, 0, 0);
                __builtin_amdgcn_global_load_lds((GAS_cv*)(vi + chunk * 1024 + lane * 16),
                    (LAS_v*)(VtB + chunk * 1024), 16, 0, 0);
            }
        }
        __syncthreads();
        f32x4 s[4];
        #pragma unroll
        for (int i = 0; i < 4; i++) { f32x4 z = {0.f,0.f,0.f,0.f}; s[i] = z; }
        #pragma unroll
        for (int ds = 0; ds < 2; ds++) {
            #pragma unroll
            for (int n = 0; n < 4; n++) {
                int r = n * 16 + fr;
                int swz = (r & 7) << 4;
                const unsigned char* rb = KhlB + r * 256;
                bf16x8 kh = *(const bf16x8*)(rb + ((ds * 64 + kg * 16) ^ swz));
                bf16x8 kl = *(const bf16x8*)(rb + 128 + ((ds * 64 + kg * 16) ^ swz));
                s[n] = __builtin_amdgcn_mfma_f32_16x16x32_bf16(qh[ds], kh, s[n], 0, 0, 0);
                s[n] = __builtin_amdgcn_mfma_f32_16x16x32_bf16(qh[ds], kl, s[n], 0, 0, 0);
                s[n] = __builtin_amdgcn_mfma_f32_16x16x32_bf16(qlo[ds], kh, s[n], 0, 0, 0);
            }
        }
        float p[4][4];
        #pragma unroll
        for (int n = 0; n < 4; n++) {
            int kcol = c0 + n * 16 + fr;
            #pragma unroll
            for (int r = 0; r < 4; r++) {
                float sv = s[n][r] * 0.125f;
                if (kcol >= SEQ) sv = -1e30f;
                p[n][r] = sv;
            }
        }
        float corr[4];
        #pragma unroll
        for (int r = 0; r < 4; r++) {
            float mx = fmaxf(fmaxf(p[0][r], p[1][r]), fmaxf(p[2][r], p[3][r]));
            mx = fmaxf(mx, __shfl_xor(mx, 1));
            mx = fmaxf(mx, __shfl_xor(mx, 2));
            mx = fmaxf(mx, __shfl_xor(mx, 4));
            mx = fmaxf(mx, __shfl_xor(mx, 8));
            float mnew = fmaxf(m_run[r], mx);
            corr[r] = __expf(m_run[r] - mnew);
            m_run[r] = mnew;
            float ls = 0.f;
            #pragma unroll
            for (int n = 0; n < 4; n++) {
                p[n][r] = __expf(p[n][r] - mnew);
                ls += p[n][r];
            }
            ls += __shfl_xor(ls, 1);
            ls += __shfl_xor(ls, 2);
            ls += __shfl_xor(ls, 4);
            ls += __shfl_xor(ls, 8);
            l_run[r] = l_run[r] * corr[r] + ls;
        }
        #pragma unroll
        for (int nd = 0; nd < 4; nd++)
            #pragma unroll
            for (int r = 0; r < 4; r++)
                acc_o[nd][r] *= corr[r];
        {
            int qb = (lane >> 4) * 4;
            #pragma unroll
            for (int n = 0; n < 4; n++) {
                int kcol = n * 16 + fr;
                #pragma unroll
                for (int r = 0; r < 4; r++) {
                    int qq = qb + r;
                    unsigned short ph = f2bf(p[n][r]);
                    unsigned short pl = f2bf(p[n][r] - bf2f(ph));
                    int off = (kcol * 2) ^ ((qq & 7) << 4);
                    *(unsigned short*)(PwB + qq * 256 + off) = ph;
                    *(unsigned short*)(PwB + qq * 256 + 128 + off) = pl;
                }
            }
        }
        #pragma unroll
        for (int ks = 0; ks < 2; ks++) {
            int swzp = (fr & 7) << 4;
            bf16x8 pah = *(const bf16x8*)(PwB + fr * 256 + ((ks * 64 + kg * 16) ^ swzp));
            bf16x8 pal = *(const bf16x8*)(PwB + fr * 256 + 128 + ((ks * 64 + kg * 16) ^ swzp));
            #pragma unroll
            for (int nd = 0; nd < 4; nd++) {
                int rv = nd * 16 + fr;
                int swzv = (rv & 7) << 4;
                const unsigned char* rb = VtB + rv * 256;
                bf16x8 vh = *(const bf16x8*)(rb + ((ks * 64 + kg * 16) ^ swzv));
                bf16x8 vl = *(const bf16x8*)(rb + 128 + ((ks * 64 + kg * 16) ^ swzv));
                acc_o[nd] = __builtin_amdgcn_mfma_f32_16x16x32_bf16(pah, vh, acc_o[nd], 0, 0, 0);
                acc_o[nd] = __builtin_amdgcn_mfma_f32_16x16x32_bf16(pah, vl, acc_o[nd], 0, 0, 0);
                acc_o[nd] = __builtin_amdgcn_mfma_f32_16x16x32_bf16(pal, vh, acc_o[nd], 0, 0, 0);
            }
        }
    }
    // epilogue: O -> plane images (global row index)
    #pragma unroll
    for (int r = 0; r < 4; r++) {
        int q = q0 + wid * 16 + (lane >> 4) * 4 + r;
        if (q >= SEQ) continue;
        float inv = 1.f / l_run[r];
        int grow = row0 + b * SEQ + q;
        int r2 = grow & 127;
        size_t ibase = (size_t)(grow >> 7) * 24;
        int swz = (r2 & 7) << 4;
        #pragma unroll
        for (int nd = 0; nd < 4; nd++) {
            int col = h * DHEAD + nd * 16 + fr;
            float v = acc_o[nd][r] * inv;
            unsigned short hh = f2bf(v);
            unsigned short ll = f2bf(v - bf2f(hh));
            unsigned char* ip = (unsigned char*)attimg + ((ibase + (col >> 5)) << 14) + r2 * 128;
            int kc = col & 31;
            *(unsigned short*)(ip + ((2 * kc) ^ swz)) = hh;
            *(unsigned short*)(ip + ((64 + 2 * kc) ^ swz)) = ll;
        }
    }
}

// ---------------- row max of symmetrized sim (excluding diagonal) ----------------
__global__ __launch_bounds__(64) void rowmax_kernel(const float* __restrict__ sim,
                                                    float* __restrict__ ms) {
    int row = blockIdx.x;
    int b = row / NIMG, n = row % NIMG;
    const float* sb = sim + (size_t)b * NIMG * NIMG;
    int lane = threadIdx.x;
    float mx = -1e30f;
    #pragma unroll
    for (int i = 0; i < NIMG / 64; i++) {
        int m = lane + i * 64;
        if (m != n) {
            float v = 0.5f * (sb[(size_t)n * NIMG + m] + sb[(size_t)m * NIMG + n]);
            mx = fmaxf(mx, v);
        }
    }
    #pragma unroll
    for (int o = 32; o; o >>= 1) mx = fmaxf(mx, __shfl_down(mx, o));
    if (lane == 0) ms[row] = mx;
}

// ---------------- exact top-k selection with lax.top_k tie semantics ----------------
__global__ __launch_bounds__(576) void select_kernel(const float* __restrict__ ms,
        int* __restrict__ mergemask, int* __restrict__ keeppos) {
    __shared__ float v[NIMG];
    __shared__ int keepf[NIMG];
    int b = blockIdx.x;
    int n = threadIdx.x;
    v[n] = ms[b * NIMG + n];
    __syncthreads();
    float vn = v[n];
    int rank_desc = 0, rank_asc = 0;
    for (int m = 0; m < NIMG; m++) {
        float vm = v[m];
        int tie_lo = (vm == vn && m < n);
        rank_desc += (vm > vn) || tie_lo;
        rank_asc  += (vm < vn) || tie_lo;
    }
    int merge = rank_desc < NMERGE;
    int keep  = rank_asc  < NMERGE;
    mergemask[b * NIMG + n] = merge;
    keepf[n] = keep;
    __syncthreads();
    if (keep) {
        int pos = 0;
        for (int m = 0; m < n; m++) pos += keepf[m];
        keeppos[b * NIMG + n] = pos;
    } else {
        keeppos[b * NIMG + n] = -1;
    }
}

// ---------------- average of merged tokens (parallelized) ----------------
__global__ __launch_bounds__(256) void avg_kernel(const float* __restrict__ x2,
        const int* __restrict__ mask, float* __restrict__ avg) {
    __shared__ float4 red[8][33];
    int b = blockIdx.x, cc = blockIdx.y;
    int t = threadIdx.x;
    int rr = t >> 5, c4 = t & 31;
    int c = cc * 128 + c4 * 4;
    const int* mb = mask + b * NIMG;
    float4 s = make_float4(0.f, 0.f, 0.f, 0.f);
    for (int n = rr; n < NIMG; n += 8) {
        if (mb[n]) {
            float4 v = *(const float4*)(x2 + ((size_t)b * SEQ + 1 + n) * CDIM + c);
            s.x += v.x; s.y += v.y; s.z += v.z; s.w += v.w;
        }
    }
    red[rr][c4] = s;
    __syncthreads();
    if (rr == 0) {
        float4 tot = red[0][c4];
        #pragma unroll
        for (int i = 1; i < 8; i++) {
            float4 v = red[i][c4];
            tot.x += v.x; tot.y += v.y; tot.z += v.z; tot.w += v.w;
        }
        float sc1 = 1.f / (float)NMERGE, sc2 = 1.f / (float)(NIMG - NMERGE);
        tot.x = (tot.x * sc1) * sc2; tot.y = (tot.y * sc1) * sc2;
        tot.z = (tot.z * sc1) * sc2; tot.w = (tot.w * sc1) * sc2;
        *(float4*)(avg + (size_t)b * CDIM + c) = tot;
    }
}

// ---------------- assemble output ----------------
__global__ __launch_bounds__(192) void assemble_kernel(const float* __restrict__ x2,
        const int* __restrict__ keeppos, const float* __restrict__ avg,
        float* __restrict__ out) {
    int g = blockIdx.x;
    int b = g / SEQ, s_ = g % SEQ;
    int t = threadIdx.x;
    const float4* src = (const float4*)(x2 + (size_t)g * CDIM);
    if (s_ == 0) {
        float4* dst = (float4*)(out + (size_t)b * 289 * CDIM);
        dst[t] = src[t];
    } else {
        int n = s_ - 1;
        int pos = keeppos[b * NIMG + n];
        if (pos < 0) return;
        const float4* av = (const float4*)(avg + (size_t)b * CDIM);
        float4 v = src[t], a = av[t];
        v.x += a.x; v.y += a.y; v.z += a.z; v.w += a.w;
        float4* dst = (float4*)(out + ((size_t)b * 289 + 1 + pos) * CDIM);
        dst[t] = v;
    }
}

extern "C" void kernel_launch(void* const* d_in, const int* in_sizes, int n_in,
                              void* d_out, int out_size, void* d_ws, size_t ws_size,
                              hipStream_t stream) {
    const float* x      = (const float*)d_in[0];
    const float* qkv_w  = (const float*)d_in[1];
    const float* qkv_b  = (const float*)d_in[2];
    const float* proj_w = (const float*)d_in[3];
    const float* proj_b = (const float*)d_in[4];
    const float* ln1_g  = (const float*)d_in[5];
    const float* ln1_b  = (const float*)d_in[6];
    const float* ln2_g  = (const float*)d_in[7];
    const float* ln2_b  = (const float*)d_in[8];
    const float* fc1_w  = (const float*)d_in[9];
    const float* fc1_b  = (const float*)d_in[10];
    const float* fc2_w  = (const float*)d_in[11];
    const float* fc2_b  = (const float*)d_in[12];

    if (ws_size < NEED_BYTES) return;

    float* ws   = (float*)d_ws;
    float* bh   = ws + O_BH;
    float* ba   = ws + O_BA;
    float* bq   = ws + O_BQ;
    float* qbuf = ws + O_BQ;
    unsigned short* kimg = (unsigned short*)(ws + O_KIMG);
    unsigned short* vimg = (unsigned short*)(ws + O_VIMG);
    float* ms   = ws + O_MS;
    int*   mask = (int*)(ws + O_MASK);
    int*   pos  = (int*)(ws + O_POS);
    float* avg  = ws + O_AVG;
    float* outp = (float*)d_out;

    unsigned short* himg   = (unsigned short*)bh;
    unsigned short* attimg = (unsigned short*)ba;
    unsigned short* h2img  = (unsigned short*)ba;
    unsigned short* xnimg  = (unsigned short*)ba;
    unsigned short* fopl   = (unsigned short*)bq;

    unsigned short* qkvp  = (unsigned short*)(outp + OW_QKV);
    unsigned short* fc1p  = (unsigned short*)(outp + OW_FC1);
    unsigned short* fc2p  = (unsigned short*)(outp + OW_FC2);
    unsigned short* projp = (unsigned short*)(outp + OW_PROJ);

    // 0. split weights; zero V-image scratch
    wsplit_kernel<<<18 * 24, 256, 0, stream>>>(qkv_w, qkvp, 24, CDIM);
    wsplit_kernel<<<24 * 24, 256, 0, stream>>>(fc1_w, fc1p, 24, CDIM);
    wsplit_kernel<<<6 * 96, 256, 0, stream>>>(fc2_w, fc2p, 96, 3072);
    wsplit_kernel<<<6 * 24, 256, 0, stream>>>(proj_w, projp, 24, CDIM);
    hipMemsetAsync(vimg, 0, SZ_IMG * 4, stream);

    // 1. h = LN1(x) -> group-padded plane images in BH
    ln_split<<<MTOK, 256, 0, stream>>>(x, ln1_g, ln1_b, himg, MGRP, 37);

    // 2. per-group qkv (128x64 dual-glds) + attention -> att images in BA
    for (int g = 0; g < NGROUP; g++) {
        gemm_ppx2<6><<<dim3(37, 36), 256, 0, stream>>>(
            himg + (size_t)g * 37 * 24 * 8192, qkvp, (void*)qbuf, 3 * CDIM,
            qkv_b, nullptr, MGRP, 3 * CDIM, CDIM, kimg, vimg);
        attn_glds<<<dim3(NKT, NHEADS, GB), 256, 0, stream>>>(
            qbuf, kimg, vimg, attimg, g * MGRP);
    }

    // 3. x1 = x + att @ proj_w^T + proj_b (128x64 dual-glds) -> BH fp32
    gemm_ppx2<1><<<dim3((MTOK + 127) / 128, 12), 256, 0, stream>>>(
        attimg, projp, (void*)bh, CDIM, proj_b, x, MTOK, CDIM, CDIM,
        nullptr, nullptr);

    // 4. h2 = LN2(x1) -> global plane images in BA
    ln_split<<<MTOK, 256, 0, stream>>>(bh, ln2_g, ln2_b, h2img, MTOK, 145);

    // 5. MLP chunks: fc1 (128x64, gelu -> fc1o images), fc2 (64x64, +res BH)
    for (int c0 = 0; c0 < MTOK; c0 += MLPCH) {
        int mc = (MTOK - c0 < MLPCH) ? (MTOK - c0) : MLPCH;
        float* x1c = bh + (size_t)c0 * CDIM;
        gemm_ppx2<5><<<dim3((mc + 127) / 128, 48), 256, 0, stream>>>(
            h2img + (size_t)(c0 >> 7) * 24 * 8192, fc1p, (void*)fopl, 3072,
            fc1_b, nullptr, mc, 3072, CDIM, nullptr, nullptr);
        gemm_ppx<1><<<dim3((mc + 63) / 64, 12), 256, 0, stream>>>(
            fopl, fc2p, (void*)x1c, CDIM, fc2_b, x1c,
            mc, CDIM, 3072, 0, 0, nullptr, nullptr);
    }

    // 6-8. two batch-halves: xn images -> batched sim (64x64) -> rowmax
    for (int hf = 0; hf < 2; hf++) {
        xn_split<<<16 * NIMG, 256, 0, stream>>>(bh, xnimg, hf * 16);
        gemm_ppx<4><<<dim3(9, 9, 16), 256, 0, stream>>>(
            xnimg, xnimg, (void*)bq, NIMG, nullptr, nullptr,
            NIMG, NIMG, CDIM, 5 * 24, (long long)NIMG * NIMG, nullptr, nullptr);
        rowmax_kernel<<<16 * NIMG, 64, 0, stream>>>(bq, ms + (size_t)hf * 16 * NIMG);
    }

    // 9-11. selection, merged average, assemble
    select_kernel<<<NBATCH, NIMG, 0, stream>>>(ms, mask, pos);
    avg_kernel<<<dim3(NBATCH, 6), 256, 0, stream>>>(bh, mask, avg);
    assemble_kernel<<<MTOK, 192, 0, stream>>>(bh, pos, avg, outp);
}